// Round 5
// baseline (9359.949 us; speedup 1.0000x reference)
//
#include <hip/hip_runtime.h>
#include <hip/hip_fp16.h>
#include <math.h>

#define Tt 64
#define Bb 16
#define Nn 256
#define Ww 64
#define Rr 4
#define INd 64
#define OUTd 64
#define IFS 471
#define EPSf 1e-6f

// transposed packed half2 layouts: element addr = row*1024 + tid
#define W1OFF   0        // 40 rows  (tid = o*4+c, k2 = c*40+j)
#define W2OFF   40960    // 32 rows  (tid = o*4+c, k2 = c*32+j)
#define WIFOFF  73728    // 64 rows  (tid = o*2+c, k2 = c*64+j; o>=471 zero)
#define WONOFF  139264   // 16 rows  (tid = o*16+c; c<8 Wout k2=c*16+j, c>=8 Wmem)
#define WTOT2   155648

// link: 256 rows x 129 dwords (258 halfs; 256 used + 2 pad)
#define LROW    129
#define LINKB   (256 * LROW * 4)     // 132096 B
#define SCRB    16384                // 4096 floats / 8192 halfs
#define FIXF    3664
#define SMEM_MAIN (LINKB + SCRB + FIXF * 4)   // 163136 <= 163840
#define SMEM_FB   (SCRB + FIXF * 4)

__device__ __forceinline__ float sigm(float x) { return 1.f / (1.f + expf(-x)); }
__device__ __forceinline__ float oneplus_(float x) {
    return 1.f + fmaxf(x, 0.f) + log1pf(expf(-fabsf(x)));
}
__device__ __forceinline__ float wsum(float v) {
#pragma unroll
    for (int o = 32; o; o >>= 1) v += __shfl_xor(v, o, 64);
    return v;
}
__device__ __forceinline__ float wmaxr(float v) {
#pragma unroll
    for (int o = 32; o; o >>= 1) v = fmaxf(v, __shfl_xor(v, o, 64));
    return v;
}

// ---- converter: fp32 weights -> transposed packed half2 ----
__global__ void convert_weights(const float* __restrict__ W1, const float* __restrict__ W2,
                                const float* __restrict__ Wif, const float* __restrict__ Wout,
                                const float* __restrict__ Wmem, __half2* __restrict__ wp) {
    int i = blockIdx.x * blockDim.x + threadIdx.x;
    if (i >= WTOT2) return;
    float a = 0.f, b = 0.f;
    if (i < W2OFF) {
        int r = i & 1023, j = i >> 10, o = r >> 2, c = r & 3, k2 = c * 40 + j;
        a = W1[(2 * k2) * 256 + o]; b = W1[(2 * k2 + 1) * 256 + o];
    } else if (i < WIFOFF) {
        int t = i - W2OFF; int r = t & 1023, j = t >> 10, o = r >> 2, c = r & 3, k2 = c * 32 + j;
        a = W2[(2 * k2) * 256 + o]; b = W2[(2 * k2 + 1) * 256 + o];
    } else if (i < WONOFF) {
        int t = i - WIFOFF; int r = t & 1023, j = t >> 10, o = r >> 1, c = r & 1, k2 = c * 64 + j;
        if (o < IFS) { a = Wif[(2 * k2) * IFS + o]; b = Wif[(2 * k2 + 1) * IFS + o]; }
    } else {
        int t = i - WONOFF; int r = t & 1023, j = t >> 10, o = r >> 4, c = r & 15;
        if (c < 8) { int k2 = c * 16 + j; a = Wout[(2 * k2) * 64 + o]; b = Wout[(2 * k2 + 1) * 64 + o]; }
        else       { int k2 = (c - 8) * 16 + j; a = Wmem[(2 * k2) * 64 + o]; b = Wmem[(2 * k2 + 1) * 64 + o]; }
    }
    wp[i] = __floats2half2_rn(a, b);
}

template <bool LLINK>
__global__ __launch_bounds__(1024, 4) void dnc_kernel(
    const float* __restrict__ x, const float* __restrict__ b1,
    const float* __restrict__ b2, const float* __restrict__ bif,
    const __half2* __restrict__ wp,
    __half* __restrict__ memg,      // per batch 64*256 halves, [w][n]
    __half2* __restrict__ linkg,    // fallback link
    float* __restrict__ out)
{
    extern __shared__ __align__(16) char smem[];
    const int b = blockIdx.x;
    const int tid = threadIdx.x;
    const int lane = tid & 63;
    const int wv = tid >> 6;

    __half2* l2p = (__half2*)smem;
    __half2* gl2 = linkg + (size_t)b * (256 * LROW);
    float* scr  = (float*)(smem + (LLINK ? LINKB : 0));
    __half* scrh = (__half*)scr;
    float* fx   = (float*)((char*)scr + SCRB);

    float* s_ctrl  = fx + 0;      // 320
    float* s_h     = fx + 320;    // 256
    float* s_nn    = fx + 576;    // 256
    float* s_z     = fx + 832;    // 472
    float* s_usage = fx + 1304;   // 256
    float* s_ww    = fx + 1560;   // 256
    float* s_prec  = fx + 1816;   // 256
    float* s_rw    = fx + 2072;   // 256*4
    float* s_wcdot = fx + 3096;   // 256
    float* s_wcss  = fx + 3352;   // 256
    float* s_knorm = fx + 3608;   // 4
    float* s_rstr  = fx + 3612;   // 4
    float* s_rmode = fx + 3616;   // 12
    float* s_sc    = fx + 3628;   // 4
    float* s_red   = fx + 3632;   // 32
    float* s_srt   = scr + 1024;  // 256 (mega only)
    float* s_cp    = scr + 1280;  // 256 (mega only)
    float* s_rvec  = scr + 1536;  // 256

    const float4* rw4 = (const float4*)s_rw;
    __half*  memh  = memg + (size_t)b * (Ww * Nn);
    __half2* memh2 = (__half2*)memh;

    auto lread = [&](int idx) -> __half2 {
        if constexpr (LLINK) return l2p[idx]; else return gl2[idx];
    };
    auto lwrite = [&](int idx, __half2 v) {
        if constexpr (LLINK) l2p[idx] = v; else gl2[idx] = v;
    };

    // ---- init ----
    {
        __half2 z2 = __floats2half2_rn(0.f, 0.f);
        for (int i = tid; i < 256 * LROW; i += 1024) lwrite(i, z2);
        __half2 e2 = __floats2half2_rn(EPSf, EPSf);
#pragma unroll
        for (int j = 0; j < 8; ++j) memh2[tid + j * 1024] = e2;
    }
    if (tid < 256) {
        s_usage[tid] = 0.f; s_ww[tid] = 0.f; s_prec[tid] = 0.f;
        s_rw[tid*4+0] = 0.f; s_rw[tid*4+1] = 0.f; s_rw[tid*4+2] = 0.f; s_rw[tid*4+3] = 0.f;
    }
    if (tid < 64) s_ctrl[tid] = x[b * INd + tid];
    else if (tid < 320) s_ctrl[tid] = 0.f;

    for (int t = 0; t < Tt; ++t) {
        __syncthreads();  // B0

        // ---- P1: h = tanh(ctrl @ W1 + b1); lane-K-split 4, shuffle reduce ----
        {
            int o = tid >> 2, c = tid & 3;
            const __half2* wP = wp + W1OFF + tid;
            float acc = 0.f;
#pragma unroll
            for (int j0 = 0; j0 < 40; j0 += 8) {
                __half2 hh[8];
#pragma unroll
                for (int u = 0; u < 8; ++u) hh[u] = wP[(j0 + u) * 1024];
#pragma unroll
                for (int u = 0; u < 8; ++u) {
                    int k2 = c * 40 + j0 + u;
                    float2 wf = __half22float2(hh[u]);
                    float2 cv = *(const float2*)&s_ctrl[2 * k2];
                    acc = fmaf(cv.x, wf.x, fmaf(cv.y, wf.y, acc));
                }
            }
            acc += __shfl_xor(acc, 1, 64); acc += __shfl_xor(acc, 2, 64);
            if (c == 0) s_h[o] = tanhf(b1[o] + acc);
        }
        __syncthreads();  // B1

        // ---- P2: nn = tanh(h @ W2 + b2) ----
        {
            int o = tid >> 2, c = tid & 3;
            const __half2* wP = wp + W2OFF + tid;
            float acc = 0.f;
#pragma unroll
            for (int j0 = 0; j0 < 32; j0 += 8) {
                __half2 hh[8];
#pragma unroll
                for (int u = 0; u < 8; ++u) hh[u] = wP[(j0 + u) * 1024];
#pragma unroll
                for (int u = 0; u < 8; ++u) {
                    int k2 = c * 32 + j0 + u;
                    float2 wf = __half22float2(hh[u]);
                    float2 cv = *(const float2*)&s_h[2 * k2];
                    acc = fmaf(cv.x, wf.x, fmaf(cv.y, wf.y, acc));
                }
            }
            acc += __shfl_xor(acc, 1, 64); acc += __shfl_xor(acc, 2, 64);
            if (c == 0) s_nn[o] = tanhf(b2[o] + acc);
        }
        __syncthreads();  // B2

        // ---- P3: z = nn @ W_if + b_if ----
        {
            int o = tid >> 1, c = tid & 1;
            const __half2* wP = wp + WIFOFF + tid;
            float acc = 0.f;
#pragma unroll
            for (int j0 = 0; j0 < 64; j0 += 8) {
                __half2 hh[8];
#pragma unroll
                for (int u = 0; u < 8; ++u) hh[u] = wP[(j0 + u) * 1024];
#pragma unroll
                for (int u = 0; u < 8; ++u) {
                    int k2 = c * 64 + j0 + u;
                    float2 wf = __half22float2(hh[u]);
                    float2 cv = *(const float2*)&s_nn[2 * k2];
                    acc = fmaf(cv.x, wf.x, fmaf(cv.y, wf.y, acc));
                }
            }
            acc += __shfl_xor(acc, 1, 64);
            if (c == 0 && o < IFS) s_z[o] = bif[o] + acc;
        }
        __syncthreads();  // B3

        // ---- P4: scalars + usage + wc dot/ss (merged wave roles) ----
        if (wv < 4) {
            float vz = s_z[lane * 4 + wv];
            float s = wsum(vz * vz);
            if (lane == 0) s_knorm[wv] = sqrtf(s) + EPSf;
        } else if (wv == 4) {
            float vz = s_z[260 + lane];
            float s = wsum(vz * vz);
            if (lane == 0) s_sc[3] = sqrtf(s) + EPSf;
        } else if (wv == 5) {
            if (lane < 4) s_rstr[lane] = oneplus_(s_z[256 + lane]);
            else if (lane >= 8 && lane < 12) {
                int r = lane - 8;
                float a = s_z[459+r], bm = s_z[463+r], c = s_z[467+r];
                float mx = fmaxf(a, fmaxf(bm, c));
                float ea = expf(a-mx), eb = expf(bm-mx), ec = expf(c-mx);
                float inv = 1.f / ((ea+eb)+ec);
                s_rmode[0*4+r] = ea*inv; s_rmode[1*4+r] = eb*inv; s_rmode[2*4+r] = ec*inv;
            } else if (lane == 16) s_sc[0] = oneplus_(s_z[324]);
            else if (lane == 17) s_sc[1] = sigm(s_z[457]);
            else if (lane == 18) s_sc[2] = sigm(s_z[458]);
        } else if (wv >= 8 && wv < 12) {
            int n = tid - 512;
            float ret = 1.f;
#pragma unroll
            for (int r = 0; r < 4; ++r) {
                float fg = sigm(s_z[453 + r]);
                ret *= 1.f - fg * s_rw[n*4 + r];
            }
            float u = s_usage[n], wwo = s_ww[n];
            s_usage[n] = (u + wwo - u * wwo) * ret;
        } else if (wv >= 12) {
            int n = tid - 768;
            float dot = 0.f, ssv = 0.f;
#pragma unroll
            for (int w0 = 0; w0 < 64; w0 += 8) {
                __half hv[8];
#pragma unroll
                for (int u = 0; u < 8; ++u) hv[u] = memh[(w0 + u) * 256 + n];
#pragma unroll
                for (int u = 0; u < 8; ++u) {
                    float m = __half2float(hv[u]);
                    ssv = fmaf(m, m, ssv);
                    dot = fmaf(m, s_z[260 + w0 + u], dot);
                }
            }
            s_wcdot[n] = dot; s_wcss[n] = ssv;
        }
        __syncthreads();  // B4

        // ---- P5: rank partials ----
        {
            int q = tid >> 8, n = tid & 255;
            float un = s_usage[n];
            float cnt = 0.f;
            int j0 = q * 64;
#pragma unroll 8
            for (int j = j0; j < j0 + 64; ++j) {
                float uj = s_usage[j];
                if (uj < un || (uj == un && j < n)) cnt += 1.f;
            }
            scr[q * 256 + n] = cnt;
        }
        __syncthreads();  // B5

        // ---- P6: mega (wave 0) ----
        if (wv == 0) {
            int rk[4]; float uu[4];
#pragma unroll
            for (int i = 0; i < 4; ++i) {
                int n = lane * 4 + i;
                float c = scr[n] + scr[256+n] + scr[512+n] + scr[768+n];
                rk[i] = (int)(c + 0.5f);
                uu[i] = s_usage[n];
                s_srt[rk[i]] = uu[i];
            }
            float4 vs = ((const float4*)s_srt)[lane];
            float p1 = vs.x * vs.y, p2 = p1 * vs.z, tot = p2 * vs.w;
            float incl = tot;
#pragma unroll
            for (int off = 1; off < 64; off <<= 1) {
                float tv = __shfl_up(incl, off, 64);
                if (lane >= off) incl *= tv;
            }
            float excl = __shfl_up(incl, 1, 64);
            if (lane == 0) excl = 1.f;
            float4 o4v; o4v.x = excl; o4v.y = excl*vs.x; o4v.z = excl*p1; o4v.w = excl*p2;
            ((float4*)s_cp)[lane] = o4v;

            float sims[4], mx = -1e30f;
#pragma unroll
            for (int i = 0; i < 4; ++i) {
                int n = lane * 4 + i;
                sims[i] = s_wcdot[n] / ((sqrtf(s_wcss[n]) + EPSf) * s_sc[3]) * s_sc[0];
                mx = fmaxf(mx, sims[i]);
            }
            mx = wmaxr(mx);
            float es[4], ls = 0.f;
#pragma unroll
            for (int i = 0; i < 4; ++i) { es[i] = expf(sims[i] - mx); ls += es[i]; }
            ls = wsum(ls);
            float ag = s_sc[1], wg = s_sc[2], inv = 1.f / ls, lw = 0.f;
#pragma unroll
            for (int i = 0; i < 4; ++i) {
                int n = lane * 4 + i;
                float alloc = (1.f - uu[i]) * s_cp[rk[i]];
                float wwn = wg * (ag * alloc + (1.f - ag) * es[i] * inv);
                s_ww[n] = wwn; lw += wwn;
            }
            lw = wsum(lw);
            if (lane == 0) s_red[0] = lw;
        }
        __syncthreads();  // B6

        // ---- P7: link col pass (batched RMW + bwd partials) || mem RMW (batched) ----
        if (tid < 512) {
            int kc = tid >> 7, p = tid & 127;
            int c0 = 2 * p, c1 = c0 + 1;
            float wwc0 = s_ww[c0], wwc1 = s_ww[c1];
            float pt0 = s_prec[c0], pt1 = s_prec[c1];
            float acc[8] = {0,0,0,0,0,0,0,0};
            int kbase = kc * 64;
#pragma unroll 2
            for (int k0 = kbase; k0 < kbase + 64; k0 += 8) {
                __half2 lv[8];
#pragma unroll
                for (int u = 0; u < 8; ++u) lv[u] = lread((k0 + u) * LROW + p);
                float l0v[8], l1v[8];
#pragma unroll
                for (int u = 0; u < 8; ++u) {
                    int k = k0 + u;
                    float wk = s_ww[k];
                    float2 lf = __half22float2(lv[u]);
                    float l0 = (1.f - wk - wwc0) * lf.x + wk * pt0;
                    float l1 = (1.f - wk - wwc1) * lf.y + wk * pt1;
                    if (k == c0) l0 = 0.f;
                    if (k == c1) l1 = 0.f;
                    l0v[u] = l0; l1v[u] = l1;
                }
#pragma unroll
                for (int u = 0; u < 8; ++u)
                    lwrite((k0 + u) * LROW + p, __floats2half2_rn(l0v[u], l1v[u]));
#pragma unroll
                for (int u = 0; u < 8; ++u) {
                    float4 r4v = rw4[k0 + u];
                    acc[0] = fmaf(l0v[u], r4v.x, acc[0]); acc[1] = fmaf(l0v[u], r4v.y, acc[1]);
                    acc[2] = fmaf(l0v[u], r4v.z, acc[2]); acc[3] = fmaf(l0v[u], r4v.w, acc[3]);
                    acc[4] = fmaf(l1v[u], r4v.x, acc[4]); acc[5] = fmaf(l1v[u], r4v.y, acc[5]);
                    acc[6] = fmaf(l1v[u], r4v.z, acc[6]); acc[7] = fmaf(l1v[u], r4v.w, acc[7]);
                }
            }
            __half2* bp = (__half2*)scrh + (kc * 128 + p) * 4;
            bp[0] = __floats2half2_rn(acc[0], acc[1]);
            bp[1] = __floats2half2_rn(acc[2], acc[3]);
            bp[2] = __floats2half2_rn(acc[4], acc[5]);
            bp[3] = __floats2half2_rn(acc[6], acc[7]);
        } else {
            int t0 = tid - 512;
            __half2 mv[16];
#pragma unroll
            for (int j = 0; j < 16; ++j) mv[j] = memh2[t0 + j * 512];
#pragma unroll
            for (int j = 0; j < 16; ++j) {
                int i2 = t0 + j * 512;
                int w = i2 >> 7, n2 = i2 & 127;
                float er = sigm(s_z[325 + w]);
                float wvv = s_z[389 + w];
                float2 mf = __half22float2(mv[j]);
                float wa = s_ww[2*n2], wb = s_ww[2*n2 + 1];
                mf.x = mf.x * (1.f - wa * er) + wa * wvv;
                mf.y = mf.y * (1.f - wb * er) + wb * wvv;
                memh2[i2] = __floats2half2_rn(mf.x, mf.y);
            }
        }
        __syncthreads();  // B7

        // ---- P8: fwd row pass (batched) + prec update ----
        {
            int q = tid >> 8, n8 = tid & 255;
            float f0 = 0.f, f1 = 0.f, f2 = 0.f, f3 = 0.f;
            int base = n8 * LROW + q * 32;
#pragma unroll
            for (int j0 = 0; j0 < 32; j0 += 8) {
                __half2 lv[8];
#pragma unroll
                for (int u = 0; u < 8; ++u) lv[u] = lread(base + j0 + u);
#pragma unroll
                for (int u = 0; u < 8; ++u) {
                    float2 lf = __half22float2(lv[u]);
                    int m = q * 64 + 2 * (j0 + u);
                    float4 wA = rw4[m], wB = rw4[m + 1];
                    f0 = fmaf(lf.x, wA.x, fmaf(lf.y, wB.x, f0));
                    f1 = fmaf(lf.x, wA.y, fmaf(lf.y, wB.y, f1));
                    f2 = fmaf(lf.x, wA.z, fmaf(lf.y, wB.z, f2));
                    f3 = fmaf(lf.x, wA.w, fmaf(lf.y, wB.w, f3));
                }
            }
            __half2* fp2 = (__half2*)(scrh + 4096) + (q * 256 + n8) * 2;
            fp2[0] = __floats2half2_rn(f0, f1);
            fp2[1] = __floats2half2_rn(f2, f3);
            if (q == 0) s_prec[n8] = (1.f - s_red[0]) * s_prec[n8] + s_ww[n8];
        }
        __syncthreads();  // B8

        // ---- P9: rc sim (batched mem reads) + bwd/fwd reduce + group max ----
        int rr = tid >> 8, n8c = tid & 255;
        float bwv = 0.f, fwv = 0.f, e_rc = 0.f, sim;
        {
#pragma unroll
            for (int kc = 0; kc < 4; ++kc)
                bwv += __half2float(scrh[(kc * 128 + (n8c >> 1)) * 8 + (n8c & 1) * 4 + rr]);
#pragma unroll
            for (int qq = 0; qq < 4; ++qq)
                fwv += __half2float(scrh[4096 + (qq * 256 + n8c) * 4 + rr]);
            float ssv = 0.f, dv = 0.f;
#pragma unroll
            for (int w0 = 0; w0 < 64; w0 += 8) {
                __half hv[8];
#pragma unroll
                for (int u = 0; u < 8; ++u) hv[u] = memh[(w0 + u) * 256 + n8c];
#pragma unroll
                for (int u = 0; u < 8; ++u) {
                    float m = __half2float(hv[u]);
                    ssv = fmaf(m, m, ssv);
                    dv = fmaf(m, s_z[(w0 + u) * 4 + rr], dv);
                }
            }
            sim = dv / ((sqrtf(ssv) + EPSf) * s_knorm[rr]) * s_rstr[rr];
            float mx = wmaxr(sim);
            if (lane == 0) s_red[wv] = mx;
        }
        __syncthreads();  // B9
        {
            float mx = fmaxf(fmaxf(s_red[rr*4+0], s_red[rr*4+1]), fmaxf(s_red[rr*4+2], s_red[rr*4+3]));
            e_rc = expf(sim - mx);
            float s = wsum(e_rc);
            if (lane == 0) s_red[16 + wv] = s;
        }
        __syncthreads();  // B10
        {
            float sm = (s_red[16+rr*4+0] + s_red[16+rr*4+1]) + (s_red[16+rr*4+2] + s_red[16+rr*4+3]);
            float rc = e_rc / sm;
            s_rw[n8c*4 + rr] = bwv * s_rmode[0*4+rr] + rc * s_rmode[1*4+rr] + fwv * s_rmode[2*4+rr];
        }
        __syncthreads();  // B11

        // ---- P12: rvec partials (batched mem reads) ----
        {
            int kc = tid >> 8, o = tid & 255, w = o >> 2, r = o & 3;
            const __half* mw = memh + w * 256 + kc * 64;
            float a = 0.f;
#pragma unroll
            for (int j0 = 0; j0 < 64; j0 += 8) {
                __half hv[8];
#pragma unroll
                for (int u = 0; u < 8; ++u) hv[u] = mw[j0 + u];
#pragma unroll
                for (int u = 0; u < 8; ++u)
                    a = fmaf(__half2float(hv[u]), s_rw[(kc * 64 + j0 + u) * 4 + r], a);
            }
            scr[kc * 256 + o] = a;
        }
        __syncthreads();  // B12

        // ---- P13: rvec reduce + ctrl staging + next-x ----
        if (tid < 256) {
            float v = (scr[tid] + scr[256+tid]) + (scr[512+tid] + scr[768+tid]);
            s_rvec[tid] = v;
            s_ctrl[64 + tid] = v;
        } else if (tid >= 512 && tid < 576) {
            if (t + 1 < Tt) s_ctrl[tid - 512] = x[((t + 1) * Bb + b) * INd + (tid - 512)];
        }
        __syncthreads();  // B13

        // ---- P14: out = nn @ W_out + rvec @ W_mem_out; 16-lane split, shuffle reduce ----
        {
            int o = tid >> 4, c = tid & 15;
            const __half2* wP = wp + WONOFF + tid;
            __half2 hh[16];
#pragma unroll
            for (int j = 0; j < 16; ++j) hh[j] = wP[j * 1024];
            float acc = 0.f;
            if (c < 8) {
#pragma unroll
                for (int j = 0; j < 16; ++j) {
                    int k2 = c * 16 + j;
                    float2 wf = __half22float2(hh[j]);
                    float2 cv = *(const float2*)&s_nn[2 * k2];
                    acc = fmaf(cv.x, wf.x, fmaf(cv.y, wf.y, acc));
                }
            } else {
#pragma unroll
                for (int j = 0; j < 16; ++j) {
                    int k2 = (c - 8) * 16 + j;
                    float2 wf = __half22float2(hh[j]);
                    float2 cv = *(const float2*)&s_rvec[2 * k2];
                    acc = fmaf(cv.x, wf.x, fmaf(cv.y, wf.y, acc));
                }
            }
            acc += __shfl_xor(acc, 1, 64); acc += __shfl_xor(acc, 2, 64);
            acc += __shfl_xor(acc, 4, 64); acc += __shfl_xor(acc, 8, 64);
            if (c == 0) out[(t * Bb + b) * OUTd + o] = acc;
        }
        // loop-top barrier covers s_ctrl writes
    }
}

extern "C" void kernel_launch(void* const* d_in, const int* in_sizes, int n_in,
                              void* d_out, int out_size, void* d_ws, size_t ws_size,
                              hipStream_t stream) {
    const float* x    = (const float*)d_in[0];
    const float* W1   = (const float*)d_in[1];
    const float* b1   = (const float*)d_in[2];
    const float* W2   = (const float*)d_in[3];
    const float* b2   = (const float*)d_in[4];
    const float* Wif  = (const float*)d_in[5];
    const float* bif  = (const float*)d_in[6];
    const float* Wout = (const float*)d_in[7];
    const float* Wmem = (const float*)d_in[8];
    float* out = (float*)d_out;

    // ws: [0, 622592) weights; [622592, +512KB) mem fp16; then fallback link.
    char* ws = (char*)d_ws;
    __half2* wp    = (__half2*)ws;
    __half*  memg  = (__half*)(ws + 622592);
    __half2* linkg = (__half2*)(ws + 622592 + 524288);

    convert_weights<<<dim3((WTOT2 + 255) / 256), dim3(256), 0, stream>>>(W1, W2, Wif, Wout, Wmem, wp);

    hipError_t rc = hipFuncSetAttribute(
        reinterpret_cast<const void*>(&dnc_kernel<true>),
        hipFuncAttributeMaxDynamicSharedMemorySize, SMEM_MAIN);
    if (rc == hipSuccess) {
        dnc_kernel<true><<<dim3(Bb), dim3(1024), SMEM_MAIN, stream>>>(
            x, b1, b2, bif, wp, memg, linkg, out);
    } else {
        dnc_kernel<false><<<dim3(Bb), dim3(1024), SMEM_FB, stream>>>(
            x, b1, b2, bif, wp, memg, linkg, out);
    }
}

// Round 6
// 5948.792 us; speedup vs baseline: 1.5734x; 1.5734x over previous
//
#include <hip/hip_runtime.h>
#include <hip/hip_fp16.h>
#include <math.h>

#define Tt 64
#define Bb 16
#define Nn 256
#define Ww 64
#define Rr 4
#define INd 64
#define OUTd 64
#define IFS 471
#define EPSf 1e-6f

// packed half2 weight layout offsets (in half2 units), pairs along K (R4 layout)
#define W1OFF   0        // 160*256
#define W2OFF   40960    // 128*256
#define WIFOFF  73728    // 128*471
#define WOUTOFF 134016   // 128*64
#define WMEMOFF 142208   // 128*64
#define WTOT    150400

// link: 256 rows x 129 dwords (258 halfs; 256 used + 2 pad)
#define LROW    129
#define LINKB   (256 * LROW * 4)     // 132096 B
#define SCRB    16384                // 4096 floats / 8192 halfs
#define FIXF    3664
#define SMEM_MAIN (LINKB + SCRB + FIXF * 4)   // 163136 <= 163840
#define SMEM_FB   (SCRB + FIXF * 4)

__device__ __forceinline__ float sigm(float x) { return 1.f / (1.f + expf(-x)); }
__device__ __forceinline__ float oneplus_(float x) {
    return 1.f + fmaxf(x, 0.f) + log1pf(expf(-fabsf(x)));
}
__device__ __forceinline__ float wsum(float v) {
#pragma unroll
    for (int o = 32; o; o >>= 1) v += __shfl_xor(v, o, 64);
    return v;
}
__device__ __forceinline__ float wmaxr(float v) {
#pragma unroll
    for (int o = 32; o; o >>= 1) v = fmaxf(v, __shfl_xor(v, o, 64));
    return v;
}

// ---- converter: fp32 weights -> packed half2 (pairs along K) ----
__global__ void convert_weights(const float* __restrict__ W1, const float* __restrict__ W2,
                                const float* __restrict__ Wif, const float* __restrict__ Wout,
                                const float* __restrict__ Wmem, __half2* __restrict__ wp) {
    int i = blockIdx.x * blockDim.x + threadIdx.x;
    if (i >= WTOT) return;
    float a, b;
    if (i < W2OFF)        { int r = i;           int k2 = r >> 8, n = r & 255; a = W1[(2*k2)*256+n];  b = W1[(2*k2+1)*256+n]; }
    else if (i < WIFOFF)  { int t = i - W2OFF;   int k2 = t >> 8, n = t & 255; a = W2[(2*k2)*256+n];  b = W2[(2*k2+1)*256+n]; }
    else if (i < WOUTOFF) { int t = i - WIFOFF;  int k2 = t / IFS, o = t - IFS*k2; a = Wif[(2*k2)*IFS+o]; b = Wif[(2*k2+1)*IFS+o]; }
    else if (i < WMEMOFF) { int t = i - WOUTOFF; int k2 = t >> 6, n = t & 63;  a = Wout[(2*k2)*64+n]; b = Wout[(2*k2+1)*64+n]; }
    else                  { int t = i - WMEMOFF; int k2 = t >> 6, n = t & 63;  a = Wmem[(2*k2)*64+n]; b = Wmem[(2*k2+1)*64+n]; }
    wp[i] = __floats2half2_rn(a, b);
}

template <bool LLINK>
__global__ __launch_bounds__(1024) void dnc_kernel(
    const float* __restrict__ x, const float* __restrict__ b1,
    const float* __restrict__ b2, const float* __restrict__ bif,
    const __half2* __restrict__ wp,
    __half* __restrict__ memg,      // per batch 64*256 halves, [w][n]
    __half2* __restrict__ linkg,    // fallback link
    float* __restrict__ out)
{
    extern __shared__ __align__(16) char smem[];
    const int b = blockIdx.x;
    const int tid = threadIdx.x;
    const int lane = tid & 63;
    const int wv = tid >> 6;

    __half2* l2p = (__half2*)smem;
    __half2* gl2 = linkg + (size_t)b * (256 * LROW);
    float* scr   = (float*)(smem + (LLINK ? LINKB : 0));
    __half* scrh = (__half*)scr;
    __half2* scrh2 = (__half2*)scr;
    float* fx    = (float*)((char*)scr + SCRB);

    float* s_ctrl  = fx + 0;      // 320
    float* s_h     = fx + 320;    // 256
    float* s_nn    = fx + 576;    // 256
    float* s_z     = fx + 832;    // 472
    float* s_usage = fx + 1304;   // 256
    float* s_ww    = fx + 1560;   // 256
    float* s_prec  = fx + 1816;   // 256
    float* s_rw    = fx + 2072;   // 256*4  [n][r]
    float* s_knorm = fx + 3608;   // 4
    float* s_rstr  = fx + 3612;   // 4
    float* s_rmode = fx + 3616;   // 12
    float* s_sc    = fx + 3628;   // 4
    float* s_red   = fx + 3632;   // 32
    // scr-region aliases (temporal reuse; see phase comments)
    float* s_srt   = scr + 1024;  // 256 (mega only)
    float* s_cp    = scr + 1280;  // 256 (mega only)
    float* s_rvec  = scr + 1536;  // 256 (rvec..out window)
    float* s_wcdot = scr + 2048;  // 256 (P4..mega window)
    float* s_wcss  = scr + 2304;  // 256 (P4..mega window)
    float* s_rwT   = scr + 2560;  // 1024 [r][n] (rw..rvec window)

    const float4* rw4 = (const float4*)s_rw;
    __half*  memh  = memg + (size_t)b * (Ww * Nn);
    __half2* memh2 = (__half2*)memh;

    auto lread = [&](int idx) -> __half2 {
        if constexpr (LLINK) return l2p[idx]; else return gl2[idx];
    };
    auto lwrite = [&](int idx, __half2 v) {
        if constexpr (LLINK) l2p[idx] = v; else gl2[idx] = v;
    };

    // ---- init (ws/LDS poisoned before every launch) ----
    {
        __half2 z2 = __floats2half2_rn(0.f, 0.f);
        for (int i = tid; i < 256 * LROW; i += 1024) lwrite(i, z2);
        __half2 e2 = __floats2half2_rn(EPSf, EPSf);
#pragma unroll
        for (int j = 0; j < 8; ++j) memh2[tid + j * 1024] = e2;
    }
    if (tid < 256) {
        s_usage[tid] = 0.f; s_ww[tid] = 0.f; s_prec[tid] = 0.f;
        s_rw[tid*4+0] = 0.f; s_rw[tid*4+1] = 0.f; s_rw[tid*4+2] = 0.f; s_rw[tid*4+3] = 0.f;
    }
    if (tid < 64) s_ctrl[tid] = x[b * INd + tid];
    else if (tid < 320) s_ctrl[tid] = 0.f;

    for (int t = 0; t < Tt; ++t) {
        __syncthreads();  // B0

        // ---- P1: GEMV1 partials (wave-uniform K-split 4) ----
        {
            int kc = wv >> 2, o = (wv & 3) * 64 + lane;
            const __half2* wP = wp + W1OFF + kc * 40 * 256 + o;
            float a[8] = {0,0,0,0,0,0,0,0};
#pragma unroll
            for (int j0 = 0; j0 < 40; j0 += 8) {
                __half2 hh[8];
#pragma unroll
                for (int u = 0; u < 8; ++u) hh[u] = wP[(j0 + u) * 256];
#pragma unroll
                for (int u = 0; u < 8; ++u) {
                    int k2 = kc * 40 + j0 + u;
                    float2 wf = __half22float2(hh[u]);
                    float2 cv = *(const float2*)&s_ctrl[2 * k2];
                    a[u] = fmaf(cv.x, wf.x, fmaf(cv.y, wf.y, a[u]));
                }
            }
            scr[kc * 256 + o] = ((a[0]+a[1])+(a[2]+a[3])) + ((a[4]+a[5])+(a[6]+a[7]));
        }
        __syncthreads();  // B1
        if (tid < 256)
            s_h[tid] = tanhf(b1[tid] + ((scr[tid] + scr[256+tid]) + (scr[512+tid] + scr[768+tid])));
        __syncthreads();  // B2

        // ---- P2: GEMV2 partials ----
        {
            int kc = wv >> 2, o = (wv & 3) * 64 + lane;
            const __half2* wP = wp + W2OFF + kc * 32 * 256 + o;
            float a[8] = {0,0,0,0,0,0,0,0};
#pragma unroll
            for (int j0 = 0; j0 < 32; j0 += 8) {
                __half2 hh[8];
#pragma unroll
                for (int u = 0; u < 8; ++u) hh[u] = wP[(j0 + u) * 256];
#pragma unroll
                for (int u = 0; u < 8; ++u) {
                    int k2 = kc * 32 + j0 + u;
                    float2 wf = __half22float2(hh[u]);
                    float2 cv = *(const float2*)&s_h[2 * k2];
                    a[u] = fmaf(cv.x, wf.x, fmaf(cv.y, wf.y, a[u]));
                }
            }
            scr[kc * 256 + o] = ((a[0]+a[1])+(a[2]+a[3])) + ((a[4]+a[5])+(a[6]+a[7]));
        }
        __syncthreads();  // B3
        if (tid < 256)
            s_nn[tid] = tanhf(b2[tid] + ((scr[tid] + scr[256+tid]) + (scr[512+tid] + scr[768+tid])));
        __syncthreads();  // B4

        // ---- P3: GEMV3 partials (K-split 2) ----
        {
            int kc = wv >> 3, o = (wv & 7) * 64 + lane;
            if (o < IFS) {
                const __half2* wP = wp + WIFOFF + kc * 64 * IFS + o;
                float a[8] = {0,0,0,0,0,0,0,0};
#pragma unroll
                for (int j0 = 0; j0 < 64; j0 += 8) {
                    __half2 hh[8];
#pragma unroll
                    for (int u = 0; u < 8; ++u) hh[u] = wP[(j0 + u) * IFS];
#pragma unroll
                    for (int u = 0; u < 8; ++u) {
                        int k2 = kc * 64 + j0 + u;
                        float2 wf = __half22float2(hh[u]);
                        float2 cv = *(const float2*)&s_nn[2 * k2];
                        a[u] = fmaf(cv.x, wf.x, fmaf(cv.y, wf.y, a[u]));
                    }
                }
                scr[kc * 512 + o] = ((a[0]+a[1])+(a[2]+a[3])) + ((a[4]+a[5])+(a[6]+a[7]));
            }
        }
        __syncthreads();  // B5
        if (tid < IFS) s_z[tid] = bif[tid] + scr[tid] + scr[512 + tid];
        __syncthreads();  // B6

        // ---- P4: scalars + usage + wc dot/ss (half2) ----
        if (wv < 4) {
            float vz = s_z[lane * 4 + wv];
            float s = wsum(vz * vz);
            if (lane == 0) s_knorm[wv] = sqrtf(s) + EPSf;
        } else if (wv == 4) {
            float vz = s_z[260 + lane];
            float s = wsum(vz * vz);
            if (lane == 0) s_sc[3] = sqrtf(s) + EPSf;
        } else if (wv == 5) {
            if (lane < 4) s_rstr[lane] = oneplus_(s_z[256 + lane]);
            else if (lane >= 8 && lane < 12) {
                int r = lane - 8;
                float a = s_z[459+r], bm = s_z[463+r], c = s_z[467+r];
                float mx = fmaxf(a, fmaxf(bm, c));
                float ea = expf(a-mx), eb = expf(bm-mx), ec = expf(c-mx);
                float inv = 1.f / ((ea+eb)+ec);
                s_rmode[0*4+r] = ea*inv; s_rmode[1*4+r] = eb*inv; s_rmode[2*4+r] = ec*inv;
            } else if (lane == 16) s_sc[0] = oneplus_(s_z[324]);
            else if (lane == 17) s_sc[1] = sigm(s_z[457]);
            else if (lane == 18) s_sc[2] = sigm(s_z[458]);
        } else if (wv >= 8 && wv < 12) {
            int n = tid - 512;
            float ret = 1.f;
#pragma unroll
            for (int r = 0; r < 4; ++r) {
                float fg = sigm(s_z[453 + r]);
                ret *= 1.f - fg * s_rw[n*4 + r];
            }
            float u = s_usage[n], wwo = s_ww[n];
            s_usage[n] = (u + wwo - u * wwo) * ret;
        } else if (wv == 12 || wv == 13) {
            int p = tid - 768;   // 0..127, n-pair
            float d0 = 0.f, d1 = 0.f, ss0 = 0.f, ss1 = 0.f;
#pragma unroll
            for (int w0 = 0; w0 < 64; w0 += 8) {
                __half2 hv[8];
#pragma unroll
                for (int u = 0; u < 8; ++u) hv[u] = memh2[(w0 + u) * 128 + p];
#pragma unroll
                for (int u = 0; u < 8; ++u) {
                    float2 m = __half22float2(hv[u]);
                    float kz = s_z[260 + w0 + u];
                    ss0 = fmaf(m.x, m.x, ss0); d0 = fmaf(m.x, kz, d0);
                    ss1 = fmaf(m.y, m.y, ss1); d1 = fmaf(m.y, kz, d1);
                }
            }
            s_wcdot[2*p] = d0; s_wcdot[2*p+1] = d1;
            s_wcss[2*p]  = ss0; s_wcss[2*p+1] = ss1;
        }
        __syncthreads();  // B7

        // ---- P5: rank partials ----
        {
            int q = tid >> 8, n = tid & 255;
            float un = s_usage[n];
            float cnt = 0.f;
            int j0 = q * 64;
#pragma unroll 8
            for (int j = j0; j < j0 + 64; ++j) {
                float uj = s_usage[j];
                if (uj < un || (uj == un && j < n)) cnt += 1.f;
            }
            scr[q * 256 + n] = cnt;
        }
        __syncthreads();  // B8

        // ---- P6: mega (wave 0) ----
        if (wv == 0) {
            int rk[4]; float uu[4];
#pragma unroll
            for (int i = 0; i < 4; ++i) {
                int n = lane * 4 + i;
                float c = scr[n] + scr[256+n] + scr[512+n] + scr[768+n];
                rk[i] = (int)(c + 0.5f);
                uu[i] = s_usage[n];
                s_srt[rk[i]] = uu[i];
            }
            float4 vs = ((const float4*)s_srt)[lane];
            float p1 = vs.x * vs.y, p2 = p1 * vs.z, tot = p2 * vs.w;
            float incl = tot;
#pragma unroll
            for (int off = 1; off < 64; off <<= 1) {
                float tv = __shfl_up(incl, off, 64);
                if (lane >= off) incl *= tv;
            }
            float excl = __shfl_up(incl, 1, 64);
            if (lane == 0) excl = 1.f;
            float4 o4v; o4v.x = excl; o4v.y = excl*vs.x; o4v.z = excl*p1; o4v.w = excl*p2;
            ((float4*)s_cp)[lane] = o4v;

            float sims[4], mx = -1e30f;
#pragma unroll
            for (int i = 0; i < 4; ++i) {
                int n = lane * 4 + i;
                sims[i] = s_wcdot[n] / ((sqrtf(s_wcss[n]) + EPSf) * s_sc[3]) * s_sc[0];
                mx = fmaxf(mx, sims[i]);
            }
            mx = wmaxr(mx);
            float es[4], ls = 0.f;
#pragma unroll
            for (int i = 0; i < 4; ++i) { es[i] = expf(sims[i] - mx); ls += es[i]; }
            ls = wsum(ls);
            float ag = s_sc[1], wg = s_sc[2], inv = 1.f / ls, lw = 0.f;
#pragma unroll
            for (int i = 0; i < 4; ++i) {
                int n = lane * 4 + i;
                float alloc = (1.f - uu[i]) * s_cp[rk[i]];
                float wwn = wg * (ag * alloc + (1.f - ag) * es[i] * inv);
                s_ww[n] = wwn; lw += wwn;
            }
            lw = wsum(lw);
            if (lane == 0) s_red[0] = lw;
        }
        __syncthreads();  // B9

        // ---- P7: link col pass (8 waves) || mem RMW (8 waves) ----
        if (tid < 512) {
            int kc = tid >> 7, p = tid & 127;
            int c0 = 2 * p, c1 = c0 + 1;
            float wwc0 = s_ww[c0], wwc1 = s_ww[c1];
            float pt0 = s_prec[c0], pt1 = s_prec[c1];
            float acc[8] = {0,0,0,0,0,0,0,0};
            int kbase = kc * 64;
#pragma unroll 2
            for (int k0 = kbase; k0 < kbase + 64; k0 += 8) {
                __half2 lv[8];
#pragma unroll
                for (int u = 0; u < 8; ++u) lv[u] = lread((k0 + u) * LROW + p);
                float l0v[8], l1v[8];
#pragma unroll
                for (int u = 0; u < 8; ++u) {
                    int k = k0 + u;
                    float wk = s_ww[k];
                    float2 lf = __half22float2(lv[u]);
                    float l0 = (1.f - wk - wwc0) * lf.x + wk * pt0;
                    float l1 = (1.f - wk - wwc1) * lf.y + wk * pt1;
                    if (k == c0) l0 = 0.f;
                    if (k == c1) l1 = 0.f;
                    l0v[u] = l0; l1v[u] = l1;
                }
#pragma unroll
                for (int u = 0; u < 8; ++u)
                    lwrite((k0 + u) * LROW + p, __floats2half2_rn(l0v[u], l1v[u]));
#pragma unroll
                for (int u = 0; u < 8; ++u) {
                    float4 r4v = rw4[k0 + u];
                    acc[0] = fmaf(l0v[u], r4v.x, acc[0]); acc[1] = fmaf(l0v[u], r4v.y, acc[1]);
                    acc[2] = fmaf(l0v[u], r4v.z, acc[2]); acc[3] = fmaf(l0v[u], r4v.w, acc[3]);
                    acc[4] = fmaf(l1v[u], r4v.x, acc[4]); acc[5] = fmaf(l1v[u], r4v.y, acc[5]);
                    acc[6] = fmaf(l1v[u], r4v.z, acc[6]); acc[7] = fmaf(l1v[u], r4v.w, acc[7]);
                }
            }
            // bwd partials: [kc][r][p] half2 (n0,n1) in scrh2[0..2048)
#pragma unroll
            for (int r = 0; r < 4; ++r)
                scrh2[(kc * 4 + r) * 128 + p] = __floats2half2_rn(acc[r], acc[4 + r]);
        } else {
            int t0 = tid - 512;
            __half2 mv[16];
#pragma unroll
            for (int j = 0; j < 16; ++j) mv[j] = memh2[t0 + j * 512];
#pragma unroll
            for (int j = 0; j < 16; ++j) {
                int i2 = t0 + j * 512;
                int w = i2 >> 7, n2 = i2 & 127;
                float er = sigm(s_z[325 + w]);
                float wvv = s_z[389 + w];
                float2 mf = __half22float2(mv[j]);
                float wa = s_ww[2*n2], wb = s_ww[2*n2 + 1];
                mf.x = mf.x * (1.f - wa * er) + wa * wvv;
                mf.y = mf.y * (1.f - wb * er) + wb * wvv;
                memh2[i2] = __floats2half2_rn(mf.x, mf.y);
            }
        }
        __syncthreads();  // B10

        // ---- P8: fwd row pass + prec update; fwd partials [q][r][n] u16 at halfs 4096.. ----
        {
            int q = tid >> 8, n8 = tid & 255;
            float f0 = 0.f, f1 = 0.f, f2 = 0.f, f3 = 0.f;
            int base = n8 * LROW + q * 32;
#pragma unroll
            for (int j0 = 0; j0 < 32; j0 += 8) {
                __half2 lv[8];
#pragma unroll
                for (int u = 0; u < 8; ++u) lv[u] = lread(base + j0 + u);
#pragma unroll
                for (int u = 0; u < 8; ++u) {
                    float2 lf = __half22float2(lv[u]);
                    int m = q * 64 + 2 * (j0 + u);
                    float4 wA = rw4[m], wB = rw4[m + 1];
                    f0 = fmaf(lf.x, wA.x, fmaf(lf.y, wB.x, f0));
                    f1 = fmaf(lf.x, wA.y, fmaf(lf.y, wB.y, f1));
                    f2 = fmaf(lf.x, wA.z, fmaf(lf.y, wB.z, f2));
                    f3 = fmaf(lf.x, wA.w, fmaf(lf.y, wB.w, f3));
                }
            }
            scrh[4096 + (q * 4 + 0) * 256 + n8] = __float2half(f0);
            scrh[4096 + (q * 4 + 1) * 256 + n8] = __float2half(f1);
            scrh[4096 + (q * 4 + 2) * 256 + n8] = __float2half(f2);
            scrh[4096 + (q * 4 + 3) * 256 + n8] = __float2half(f3);
            if (q == 0) s_prec[n8] = (1.f - s_red[0]) * s_prec[n8] + s_ww[n8];
        }
        __syncthreads();  // B11

        // ---- P9: rc sim on n-pairs (8 waves) + x-prefetch (wave 8) ----
        int rr = wv >> 1, pp = ((wv & 1) << 6) | lane;   // r, n-pair
        float sim0 = 0.f, sim1 = 0.f, e0 = 0.f, e1 = 0.f;
        float bw0 = 0.f, bw1 = 0.f, fw0 = 0.f, fw1 = 0.f;
        if (wv < 8) {
#pragma unroll
            for (int kc = 0; kc < 4; ++kc) {
                float2 bp = __half22float2(scrh2[(kc * 4 + rr) * 128 + pp]);
                bw0 += bp.x; bw1 += bp.y;
            }
#pragma unroll
            for (int q = 0; q < 4; ++q) {
                float2 fp = __half22float2(scrh2[2048 + (q * 4 + rr) * 128 + pp]);
                fw0 += fp.x; fw1 += fp.y;
            }
            float d0 = 0.f, d1 = 0.f, ss0 = 0.f, ss1 = 0.f;
#pragma unroll
            for (int w0 = 0; w0 < 64; w0 += 8) {
                __half2 hv[8];
#pragma unroll
                for (int u = 0; u < 8; ++u) hv[u] = memh2[(w0 + u) * 128 + pp];
#pragma unroll
                for (int u = 0; u < 8; ++u) {
                    float2 m = __half22float2(hv[u]);
                    float kz = s_z[(w0 + u) * 4 + rr];
                    ss0 = fmaf(m.x, m.x, ss0); d0 = fmaf(m.x, kz, d0);
                    ss1 = fmaf(m.y, m.y, ss1); d1 = fmaf(m.y, kz, d1);
                }
            }
            float sc = s_rstr[rr] / s_knorm[rr];
            sim0 = d0 / (sqrtf(ss0) + EPSf) * sc;
            sim1 = d1 / (sqrtf(ss1) + EPSf) * sc;
            float mx = wmaxr(fmaxf(sim0, sim1));
            if (lane == 0) s_red[wv] = mx;
        } else if (wv == 8) {
            if (t + 1 < Tt) s_ctrl[lane] = x[((t + 1) * Bb + b) * INd + lane];
        }
        __syncthreads();  // B12
        if (wv < 8) {
            float mx = fmaxf(s_red[rr * 2], s_red[rr * 2 + 1]);
            e0 = expf(sim0 - mx); e1 = expf(sim1 - mx);
            float s = wsum(e0 + e1);
            if (lane == 0) s_red[8 + wv] = s;
        }
        __syncthreads();  // B13
        if (wv < 8) {
            float sm = s_red[8 + rr * 2] + s_red[8 + rr * 2 + 1];
            float m0 = s_rmode[0*4+rr], m1 = s_rmode[1*4+rr], m2 = s_rmode[2*4+rr];
            float v0 = bw0 * m0 + (e0 / sm) * m1 + fw0 * m2;
            float v1 = bw1 * m0 + (e1 / sm) * m1 + fw1 * m2;
            s_rw[(2*pp) * 4 + rr] = v0;
            s_rw[(2*pp+1) * 4 + rr] = v1;
            float2 vt; vt.x = v0; vt.y = v1;
            *(float2*)&s_rwT[rr * 256 + 2 * pp] = vt;
        }
        __syncthreads();  // B14

        // ---- P12: rvec direct (4 waves) + ctrl staging ----
        if (tid < 256) {
            int w = tid >> 2, r = tid & 3;
            const float* rwT = s_rwT + r * 256;
            float a = 0.f;
#pragma unroll
            for (int j0 = 0; j0 < 64; j0 += 8) {
                __half2 hv[8];
#pragma unroll
                for (int u = 0; u < 8; ++u) hv[u] = memh2[w * 128 + j0 + u];
#pragma unroll
                for (int u = 0; u < 8; ++u) {
                    float2 m = __half22float2(hv[u]);
                    float2 rv = *(const float2*)&rwT[2 * (j0 + u)];
                    a = fmaf(m.x, rv.x, fmaf(m.y, rv.y, a));
                }
            }
            s_rvec[tid] = a;
            s_ctrl[64 + tid] = a;
        }
        __syncthreads();  // B15

        // ---- P14: out GEMV partials (wave-uniform K-split 16) ----
        {
            int c4 = wv, o4 = lane;
            const __half2* wsrc = (c4 < 8) ? (wp + WOUTOFF + (c4 * 16) * 64 + o4)
                                           : (wp + WMEMOFF + ((c4 - 8) * 16) * 64 + o4);
            const float* vsrc = (c4 < 8) ? (s_nn + c4 * 32) : (s_rvec + (c4 - 8) * 32);
            float acc = 0.f;
#pragma unroll
            for (int j = 0; j < 16; ++j) {
                float2 wf = __half22float2(wsrc[j * 64]);
                float2 vv = *(const float2*)&vsrc[2 * j];
                acc = fmaf(vv.x, wf.x, fmaf(vv.y, wf.y, acc));
            }
            scr[c4 * 64 + o4] = acc;
        }
        __syncthreads();  // B16
        if (tid < 64) {
            float s = 0.f;
#pragma unroll
            for (int g = 0; g < 16; ++g) s += scr[g * 64 + tid];
            out[(t * Bb + b) * OUTd + tid] = s;
        }
        // loop-top barrier covers remaining hazards
    }
}

extern "C" void kernel_launch(void* const* d_in, const int* in_sizes, int n_in,
                              void* d_out, int out_size, void* d_ws, size_t ws_size,
                              hipStream_t stream) {
    const float* x    = (const float*)d_in[0];
    const float* W1   = (const float*)d_in[1];
    const float* b1   = (const float*)d_in[2];
    const float* W2   = (const float*)d_in[3];
    const float* b2   = (const float*)d_in[4];
    const float* Wif  = (const float*)d_in[5];
    const float* bif  = (const float*)d_in[6];
    const float* Wout = (const float*)d_in[7];
    const float* Wmem = (const float*)d_in[8];
    float* out = (float*)d_out;

    // ws: [0, 601600) packed half2 weights; [601600, +512KB) mem fp16; then fallback link.
    char* ws = (char*)d_ws;
    __half2* wp    = (__half2*)ws;
    __half*  memg  = (__half*)(ws + 601600);
    __half2* linkg = (__half2*)(ws + 601600 + 524288);

    convert_weights<<<dim3((WTOT + 255) / 256), dim3(256), 0, stream>>>(W1, W2, Wif, Wout, Wmem, wp);

    hipError_t rc = hipFuncSetAttribute(
        reinterpret_cast<const void*>(&dnc_kernel<true>),
        hipFuncAttributeMaxDynamicSharedMemorySize, SMEM_MAIN);
    if (rc == hipSuccess) {
        dnc_kernel<true><<<dim3(Bb), dim3(1024), SMEM_MAIN, stream>>>(
            x, b1, b2, bif, wp, memg, linkg, out);
    } else {
        dnc_kernel<false><<<dim3(Bb), dim3(1024), SMEM_FB, stream>>>(
            x, b1, b2, bif, wp, memg, linkg, out);
    }
}

// Round 7
// 2819.372 us; speedup vs baseline: 3.3199x; 2.1100x over previous
//
#include <hip/hip_runtime.h>
#include <hip/hip_fp16.h>
#include <math.h>

#define Tt 64
#define Bb 16
#define Nn 256
#define Ww 64
#define Rr 4
#define INd 64
#define OUTd 64
#define IFS 471
#define EPSf 1e-6f

// packed half2 weight layout offsets (in half2 units), pairs along K
#define W1OFF   0        // 160*256
#define W2OFF   40960    // 128*256
#define WIFOFF  73728    // 128*471
#define WOUTOFF 134016   // 128*64
#define WMEMOFF 142208   // 128*64
#define WTOT    150400

// link: 256 rows x 129 dwords (258 halfs; 256 used + 2 pad)
#define LROW    129
#define LINKB   (256 * LROW * 4)     // 132096 B
#define SCRB    16384                // 4096 floats / 8192 halfs
#define FIXF    3664
#define SMEM_MAIN (LINKB + SCRB + FIXF * 4)   // 163136 <= 163840
#define SMEM_FB   (SCRB + FIXF * 4)

__device__ __forceinline__ float sigm(float x) { return 1.f / (1.f + expf(-x)); }
__device__ __forceinline__ float oneplus_(float x) {
    return 1.f + fmaxf(x, 0.f) + log1pf(expf(-fabsf(x)));
}
__device__ __forceinline__ float wsum(float v) {
#pragma unroll
    for (int o = 32; o; o >>= 1) v += __shfl_xor(v, o, 64);
    return v;
}
__device__ __forceinline__ float wmaxr(float v) {
#pragma unroll
    for (int o = 32; o; o >>= 1) v = fmaxf(v, __shfl_xor(v, o, 64));
    return v;
}

// shared GEMV-partial body for P1/P2/P3/out: dot of half2 weight column (runtime
// stride) against fp32 vector in LDS. noinline -> one copy in icache.
__device__ __attribute__((noinline)) float gemv_part(
    const __half2* __restrict__ wP, int stride, int iters,
    const float* __restrict__ vin)
{
    float a[8] = {0.f,0.f,0.f,0.f,0.f,0.f,0.f,0.f};
#pragma unroll 1
    for (int j0 = 0; j0 < iters; j0 += 8) {
        __half2 hh[8];
#pragma unroll
        for (int u = 0; u < 8; ++u) hh[u] = wP[(j0 + u) * stride];
#pragma unroll
        for (int u = 0; u < 8; ++u) {
            float2 wf = __half22float2(hh[u]);
            float2 cv = *(const float2*)&vin[2 * (j0 + u)];
            a[u] = fmaf(cv.x, wf.x, fmaf(cv.y, wf.y, a[u]));
        }
    }
    return ((a[0]+a[1])+(a[2]+a[3])) + ((a[4]+a[5])+(a[6]+a[7]));
}

// ---- converter: fp32 weights -> packed half2 (pairs along K) ----
__global__ void convert_weights(const float* __restrict__ W1, const float* __restrict__ W2,
                                const float* __restrict__ Wif, const float* __restrict__ Wout,
                                const float* __restrict__ Wmem, __half2* __restrict__ wp) {
    int i = blockIdx.x * blockDim.x + threadIdx.x;
    if (i >= WTOT) return;
    float a, b;
    if (i < W2OFF)        { int r = i;           int k2 = r >> 8, n = r & 255; a = W1[(2*k2)*256+n];  b = W1[(2*k2+1)*256+n]; }
    else if (i < WIFOFF)  { int t = i - W2OFF;   int k2 = t >> 8, n = t & 255; a = W2[(2*k2)*256+n];  b = W2[(2*k2+1)*256+n]; }
    else if (i < WOUTOFF) { int t = i - WIFOFF;  int k2 = t / IFS, o = t - IFS*k2; a = Wif[(2*k2)*IFS+o]; b = Wif[(2*k2+1)*IFS+o]; }
    else if (i < WMEMOFF) { int t = i - WOUTOFF; int k2 = t >> 6, n = t & 63;  a = Wout[(2*k2)*64+n]; b = Wout[(2*k2+1)*64+n]; }
    else                  { int t = i - WMEMOFF; int k2 = t >> 6, n = t & 63;  a = Wmem[(2*k2)*64+n]; b = Wmem[(2*k2+1)*64+n]; }
    wp[i] = __floats2half2_rn(a, b);
}

template <bool LLINK>
__global__ __launch_bounds__(1024) void dnc_kernel(
    const float* __restrict__ x, const float* __restrict__ b1,
    const float* __restrict__ b2, const float* __restrict__ bif,
    const __half2* __restrict__ wp,
    __half* __restrict__ memg,      // per batch 64*256 halves, [w][n]
    __half2* __restrict__ linkg,    // fallback link
    float* __restrict__ out)
{
    extern __shared__ __align__(16) char smem[];
    const int b = blockIdx.x;
    const int tid = threadIdx.x;
    const int lane = tid & 63;
    const int wv = tid >> 6;

    __half2* l2p = (__half2*)smem;
    __half2* gl2 = linkg + (size_t)b * (256 * LROW);
    float* scr   = (float*)(smem + (LLINK ? LINKB : 0));
    __half* scrh = (__half*)scr;
    float* fx    = (float*)((char*)scr + SCRB);

    float* s_ctrl  = fx + 0;      // 320
    float* s_h     = fx + 320;    // 256
    float* s_nn    = fx + 576;    // 256
    float* s_z     = fx + 832;    // 472
    float* s_usage = fx + 1304;   // 256
    float* s_ww    = fx + 1560;   // 256
    float* s_prec  = fx + 1816;   // 256
    float* s_rw    = fx + 2072;   // 256*4  [n][r]
    float* s_wcdot = fx + 3096;   // 256
    float* s_wcss  = fx + 3352;   // 256
    float* s_knorm = fx + 3608;   // 4
    float* s_rstr  = fx + 3612;   // 4
    float* s_rmode = fx + 3616;   // 12
    float* s_sc    = fx + 3628;   // 4
    float* s_red   = fx + 3632;   // 32
    float* s_srt   = scr + 1024;  // 256 (mega only)
    float* s_cp    = scr + 1280;  // 256 (mega only)
    float* s_rvec  = scr + 1536;  // 256 (rvec..out window)

    const float4* rw4 = (const float4*)s_rw;
    __half*  memh  = memg + (size_t)b * (Ww * Nn);
    __half2* memh2 = (__half2*)memh;

    auto lread = [&](int idx) -> __half2 {
        if constexpr (LLINK) return l2p[idx]; else return gl2[idx];
    };
    auto lwrite = [&](int idx, __half2 v) {
        if constexpr (LLINK) l2p[idx] = v; else gl2[idx] = v;
    };

    // ---- init (ws/LDS poisoned before every launch) ----
    {
        __half2 z2 = __floats2half2_rn(0.f, 0.f);
#pragma unroll 1
        for (int i = tid; i < 256 * LROW; i += 1024) lwrite(i, z2);
        __half2 e2 = __floats2half2_rn(EPSf, EPSf);
#pragma unroll 1
        for (int j = 0; j < 8; ++j) memh2[tid + j * 1024] = e2;
    }
    if (tid < 256) {
        s_usage[tid] = 0.f; s_ww[tid] = 0.f; s_prec[tid] = 0.f;
        s_rw[tid*4+0] = 0.f; s_rw[tid*4+1] = 0.f; s_rw[tid*4+2] = 0.f; s_rw[tid*4+3] = 0.f;
    }
    if (tid < 64) s_ctrl[tid] = x[b * INd + tid];
    else if (tid < 320) s_ctrl[tid] = 0.f;

#pragma unroll 1
    for (int t = 0; t < Tt; ++t) {
        __syncthreads();  // B0

        // ---- P1: GEMV1 partials (wave-uniform K-split 4) ----
        {
            int kc = wv >> 2, o = (wv & 3) * 64 + lane;
            scr[kc * 256 + o] = gemv_part(wp + W1OFF + kc * 40 * 256 + o, 256, 40,
                                          s_ctrl + 2 * kc * 40);
        }
        __syncthreads();  // B1
        if (tid < 256)
            s_h[tid] = tanhf(b1[tid] + ((scr[tid] + scr[256+tid]) + (scr[512+tid] + scr[768+tid])));
        __syncthreads();  // B2

        // ---- P2: GEMV2 partials ----
        {
            int kc = wv >> 2, o = (wv & 3) * 64 + lane;
            scr[kc * 256 + o] = gemv_part(wp + W2OFF + kc * 32 * 256 + o, 256, 32,
                                          s_h + 2 * kc * 32);
        }
        __syncthreads();  // B3
        if (tid < 256)
            s_nn[tid] = tanhf(b2[tid] + ((scr[tid] + scr[256+tid]) + (scr[512+tid] + scr[768+tid])));
        __syncthreads();  // B4

        // ---- P3: GEMV3 partials (K-split 2) ----
        {
            int kc = wv >> 3, o = (wv & 7) * 64 + lane;
            if (o < IFS)
                scr[kc * 512 + o] = gemv_part(wp + WIFOFF + kc * 64 * IFS + o, IFS, 64,
                                              s_nn + 2 * kc * 64);
        }
        __syncthreads();  // B5
        if (tid < IFS) s_z[tid] = bif[tid] + scr[tid] + scr[512 + tid];
        __syncthreads();  // B6

        // ---- P4: scalars + usage + wc dot/ss (merged wave roles) ----
        if (wv < 4) {
            float vz = s_z[lane * 4 + wv];
            float s = wsum(vz * vz);
            if (lane == 0) s_knorm[wv] = sqrtf(s) + EPSf;
        } else if (wv == 4) {
            float vz = s_z[260 + lane];
            float s = wsum(vz * vz);
            if (lane == 0) s_sc[3] = sqrtf(s) + EPSf;
        } else if (wv == 5) {
            if (lane < 4) s_rstr[lane] = oneplus_(s_z[256 + lane]);
            else if (lane >= 8 && lane < 12) {
                int r = lane - 8;
                float a = s_z[459+r], bm = s_z[463+r], c = s_z[467+r];
                float mx = fmaxf(a, fmaxf(bm, c));
                float ea = expf(a-mx), eb = expf(bm-mx), ec = expf(c-mx);
                float inv = 1.f / ((ea+eb)+ec);
                s_rmode[0*4+r] = ea*inv; s_rmode[1*4+r] = eb*inv; s_rmode[2*4+r] = ec*inv;
            } else if (lane == 16) s_sc[0] = oneplus_(s_z[324]);
            else if (lane == 17) s_sc[1] = sigm(s_z[457]);
            else if (lane == 18) s_sc[2] = sigm(s_z[458]);
        } else if (wv >= 8 && wv < 12) {
            int n = tid - 512;
            float ret = 1.f;
#pragma unroll
            for (int r = 0; r < 4; ++r) {
                float fg = sigm(s_z[453 + r]);
                ret *= 1.f - fg * s_rw[n*4 + r];
            }
            float u = s_usage[n], wwo = s_ww[n];
            s_usage[n] = (u + wwo - u * wwo) * ret;
        } else if (wv >= 12) {
            int n = tid - 768;
            float dot = 0.f, ssv = 0.f;
#pragma unroll 1
            for (int w0 = 0; w0 < 64; w0 += 8) {
                __half hv[8];
#pragma unroll
                for (int u = 0; u < 8; ++u) hv[u] = memh[(w0 + u) * 256 + n];
#pragma unroll
                for (int u = 0; u < 8; ++u) {
                    float m = __half2float(hv[u]);
                    ssv = fmaf(m, m, ssv);
                    dot = fmaf(m, s_z[260 + w0 + u], dot);
                }
            }
            s_wcdot[n] = dot; s_wcss[n] = ssv;
        }
        __syncthreads();  // B7

        // ---- P5: rank partials ----
        {
            int q = tid >> 8, n = tid & 255;
            float un = s_usage[n];
            float cnt = 0.f;
            int j0 = q * 64;
#pragma unroll 1
            for (int j = j0; j < j0 + 64; ++j) {
                float uj = s_usage[j];
                if (uj < un || (uj == un && j < n)) cnt += 1.f;
            }
            scr[q * 256 + n] = cnt;
        }
        __syncthreads();  // B8

        // ---- P6: mega (wave 0) ----
        if (wv == 0) {
            int rk[4]; float uu[4];
#pragma unroll
            for (int i = 0; i < 4; ++i) {
                int n = lane * 4 + i;
                float c = scr[n] + scr[256+n] + scr[512+n] + scr[768+n];
                rk[i] = (int)(c + 0.5f);
                uu[i] = s_usage[n];
                s_srt[rk[i]] = uu[i];
            }
            float4 vs = ((const float4*)s_srt)[lane];
            float p1 = vs.x * vs.y, p2 = p1 * vs.z, tot = p2 * vs.w;
            float incl = tot;
#pragma unroll
            for (int off = 1; off < 64; off <<= 1) {
                float tv = __shfl_up(incl, off, 64);
                if (lane >= off) incl *= tv;
            }
            float excl = __shfl_up(incl, 1, 64);
            if (lane == 0) excl = 1.f;
            float4 o4v; o4v.x = excl; o4v.y = excl*vs.x; o4v.z = excl*p1; o4v.w = excl*p2;
            ((float4*)s_cp)[lane] = o4v;

            float sims[4], mx = -1e30f;
#pragma unroll
            for (int i = 0; i < 4; ++i) {
                int n = lane * 4 + i;
                sims[i] = s_wcdot[n] / ((sqrtf(s_wcss[n]) + EPSf) * s_sc[3]) * s_sc[0];
                mx = fmaxf(mx, sims[i]);
            }
            mx = wmaxr(mx);
            float es[4], ls = 0.f;
#pragma unroll
            for (int i = 0; i < 4; ++i) { es[i] = expf(sims[i] - mx); ls += es[i]; }
            ls = wsum(ls);
            float ag = s_sc[1], wg = s_sc[2], inv = 1.f / ls, lw = 0.f;
#pragma unroll
            for (int i = 0; i < 4; ++i) {
                int n = lane * 4 + i;
                float alloc = (1.f - uu[i]) * s_cp[rk[i]];
                float wwn = wg * (ag * alloc + (1.f - ag) * es[i] * inv);
                s_ww[n] = wwn; lw += wwn;
            }
            lw = wsum(lw);
            if (lane == 0) s_red[0] = lw;
        }
        __syncthreads();  // B9

        // ---- P7: link col pass (8 waves) || mem RMW (8 waves) ----
        if (tid < 512) {
            int kc = tid >> 7, p = tid & 127;
            int c0 = 2 * p, c1 = c0 + 1;
            float wwc0 = s_ww[c0], wwc1 = s_ww[c1];
            float pt0 = s_prec[c0], pt1 = s_prec[c1];
            float acc[8] = {0,0,0,0,0,0,0,0};
            int kbase = kc * 64;
#pragma unroll 1
            for (int k0 = kbase; k0 < kbase + 64; k0 += 8) {
                __half2 lv[8];
#pragma unroll
                for (int u = 0; u < 8; ++u) lv[u] = lread((k0 + u) * LROW + p);
                float l0v[8], l1v[8];
#pragma unroll
                for (int u = 0; u < 8; ++u) {
                    int k = k0 + u;
                    float wk = s_ww[k];
                    float2 lf = __half22float2(lv[u]);
                    float l0 = (1.f - wk - wwc0) * lf.x + wk * pt0;
                    float l1 = (1.f - wk - wwc1) * lf.y + wk * pt1;
                    if (k == c0) l0 = 0.f;
                    if (k == c1) l1 = 0.f;
                    l0v[u] = l0; l1v[u] = l1;
                }
#pragma unroll
                for (int u = 0; u < 8; ++u)
                    lwrite((k0 + u) * LROW + p, __floats2half2_rn(l0v[u], l1v[u]));
#pragma unroll
                for (int u = 0; u < 8; ++u) {
                    float4 r4v = rw4[k0 + u];
                    acc[0] = fmaf(l0v[u], r4v.x, acc[0]); acc[1] = fmaf(l0v[u], r4v.y, acc[1]);
                    acc[2] = fmaf(l0v[u], r4v.z, acc[2]); acc[3] = fmaf(l0v[u], r4v.w, acc[3]);
                    acc[4] = fmaf(l1v[u], r4v.x, acc[4]); acc[5] = fmaf(l1v[u], r4v.y, acc[5]);
                    acc[6] = fmaf(l1v[u], r4v.z, acc[6]); acc[7] = fmaf(l1v[u], r4v.w, acc[7]);
                }
            }
            __half2* bp = (__half2*)scrh + (kc * 128 + p) * 4;
            bp[0] = __floats2half2_rn(acc[0], acc[1]);
            bp[1] = __floats2half2_rn(acc[2], acc[3]);
            bp[2] = __floats2half2_rn(acc[4], acc[5]);
            bp[3] = __floats2half2_rn(acc[6], acc[7]);
        } else {
            int t0 = tid - 512;
#pragma unroll 1
            for (int jb = 0; jb < 2; ++jb) {
                __half2 mv[8];
#pragma unroll
                for (int j = 0; j < 8; ++j) mv[j] = memh2[t0 + (jb * 8 + j) * 512];
#pragma unroll
                for (int j = 0; j < 8; ++j) {
                    int i2 = t0 + (jb * 8 + j) * 512;
                    int w = i2 >> 7, n2 = i2 & 127;
                    float er = sigm(s_z[325 + w]);
                    float wvv = s_z[389 + w];
                    float2 mf = __half22float2(mv[j]);
                    float wa = s_ww[2*n2], wb = s_ww[2*n2 + 1];
                    mf.x = mf.x * (1.f - wa * er) + wa * wvv;
                    mf.y = mf.y * (1.f - wb * er) + wb * wvv;
                    memh2[i2] = __floats2half2_rn(mf.x, mf.y);
                }
            }
        }
        __syncthreads();  // B10

        // ---- P8: fwd row pass + prec update ----
        {
            int q = tid >> 8, n8 = tid & 255;
            float f0 = 0.f, f1 = 0.f, f2 = 0.f, f3 = 0.f;
            int base = n8 * LROW + q * 32;
#pragma unroll 1
            for (int j0 = 0; j0 < 32; j0 += 8) {
                __half2 lv[8];
#pragma unroll
                for (int u = 0; u < 8; ++u) lv[u] = lread(base + j0 + u);
#pragma unroll
                for (int u = 0; u < 8; ++u) {
                    float2 lf = __half22float2(lv[u]);
                    int m = q * 64 + 2 * (j0 + u);
                    float4 wA = rw4[m], wB = rw4[m + 1];
                    f0 = fmaf(lf.x, wA.x, fmaf(lf.y, wB.x, f0));
                    f1 = fmaf(lf.x, wA.y, fmaf(lf.y, wB.y, f1));
                    f2 = fmaf(lf.x, wA.z, fmaf(lf.y, wB.z, f2));
                    f3 = fmaf(lf.x, wA.w, fmaf(lf.y, wB.w, f3));
                }
            }
            __half2* fp2 = (__half2*)(scrh + 4096) + (q * 256 + n8) * 2;
            fp2[0] = __floats2half2_rn(f0, f1);
            fp2[1] = __floats2half2_rn(f2, f3);
            if (q == 0) s_prec[n8] = (1.f - s_red[0]) * s_prec[n8] + s_ww[n8];
        }
        __syncthreads();  // B11

        // ---- P9: rc sim + bwd/fwd reduce ----
        int rr = tid >> 8, n8c = tid & 255;
        float bwv = 0.f, fwv = 0.f, e_rc = 0.f, sim;
        {
#pragma unroll
            for (int kc = 0; kc < 4; ++kc)
                bwv += __half2float(scrh[(kc * 128 + (n8c >> 1)) * 8 + (n8c & 1) * 4 + rr]);
#pragma unroll
            for (int qq = 0; qq < 4; ++qq)
                fwv += __half2float(scrh[4096 + (qq * 256 + n8c) * 4 + rr]);
            float ssv = 0.f, dv = 0.f;
#pragma unroll 1
            for (int w0 = 0; w0 < 64; w0 += 8) {
                __half hv[8];
#pragma unroll
                for (int u = 0; u < 8; ++u) hv[u] = memh[(w0 + u) * 256 + n8c];
#pragma unroll
                for (int u = 0; u < 8; ++u) {
                    float m = __half2float(hv[u]);
                    ssv = fmaf(m, m, ssv);
                    dv = fmaf(m, s_z[(w0 + u) * 4 + rr], dv);
                }
            }
            sim = dv / ((sqrtf(ssv) + EPSf) * s_knorm[rr]) * s_rstr[rr];
            float mx = wmaxr(sim);
            if (lane == 0) s_red[wv] = mx;
        }
        __syncthreads();  // B12
        {
            float mx = fmaxf(fmaxf(s_red[rr*4+0], s_red[rr*4+1]), fmaxf(s_red[rr*4+2], s_red[rr*4+3]));
            e_rc = expf(sim - mx);
            float s = wsum(e_rc);
            if (lane == 0) s_red[16 + wv] = s;
        }
        __syncthreads();  // B13
        {
            float sm = (s_red[16+rr*4+0] + s_red[16+rr*4+1]) + (s_red[16+rr*4+2] + s_red[16+rr*4+3]);
            float rc = e_rc / sm;
            s_rw[n8c*4 + rr] = bwv * s_rmode[0*4+rr] + rc * s_rmode[1*4+rr] + fwv * s_rmode[2*4+rr];
        }
        __syncthreads();  // B14

        // ---- P12: rvec partials ----
        {
            int kc = tid >> 8, o = tid & 255, w = o >> 2, r = o & 3;
            const __half* mw = memh + w * 256 + kc * 64;
            float a = 0.f;
#pragma unroll 1
            for (int j0 = 0; j0 < 64; j0 += 8) {
                __half hv[8];
#pragma unroll
                for (int u = 0; u < 8; ++u) hv[u] = mw[j0 + u];
#pragma unroll
                for (int u = 0; u < 8; ++u)
                    a = fmaf(__half2float(hv[u]), s_rw[(kc * 64 + j0 + u) * 4 + r], a);
            }
            scr[kc * 256 + o] = a;
        }
        __syncthreads();  // B15

        // ---- P13: rvec reduce + ctrl staging + next-x ----
        if (tid < 256) {
            float v = (scr[tid] + scr[256+tid]) + (scr[512+tid] + scr[768+tid]);
            s_rvec[tid] = v;
            s_ctrl[64 + tid] = v;
        } else if (tid >= 512 && tid < 576) {
            if (t + 1 < Tt) s_ctrl[tid - 512] = x[((t + 1) * Bb + b) * INd + (tid - 512)];
        }
        __syncthreads();  // B16

        // ---- P14: out GEMV partials (shared gemv_part) ----
        {
            int c4 = wv, o4 = lane;
            const __half2* wsrc = (c4 < 8) ? (wp + WOUTOFF + (c4 * 16) * 64 + o4)
                                           : (wp + WMEMOFF + ((c4 - 8) * 16) * 64 + o4);
            const float* vsrc = (c4 < 8) ? (s_nn + c4 * 32) : (s_rvec + (c4 - 8) * 32);
            scr[c4 * 64 + o4] = gemv_part(wsrc, 64, 16, vsrc);
        }
        __syncthreads();  // B17
        if (tid < 64) {
            float s = 0.f;
#pragma unroll
            for (int g = 0; g < 16; ++g) s += scr[g * 64 + tid];
            out[(t * Bb + b) * OUTd + tid] = s;
        }
        // loop-top barrier covers remaining hazards
    }
}

extern "C" void kernel_launch(void* const* d_in, const int* in_sizes, int n_in,
                              void* d_out, int out_size, void* d_ws, size_t ws_size,
                              hipStream_t stream) {
    const float* x    = (const float*)d_in[0];
    const float* W1   = (const float*)d_in[1];
    const float* b1   = (const float*)d_in[2];
    const float* W2   = (const float*)d_in[3];
    const float* b2   = (const float*)d_in[4];
    const float* Wif  = (const float*)d_in[5];
    const float* bif  = (const float*)d_in[6];
    const float* Wout = (const float*)d_in[7];
    const float* Wmem = (const float*)d_in[8];
    float* out = (float*)d_out;

    // ws: [0, 601600) packed half2 weights; [601600, +512KB) mem fp16; then fallback link.
    char* ws = (char*)d_ws;
    __half2* wp    = (__half2*)ws;
    __half*  memg  = (__half*)(ws + 601600);
    __half2* linkg = (__half2*)(ws + 601600 + 524288);

    convert_weights<<<dim3((WTOT + 255) / 256), dim3(256), 0, stream>>>(W1, W2, Wif, Wout, Wmem, wp);

    hipError_t rc = hipFuncSetAttribute(
        reinterpret_cast<const void*>(&dnc_kernel<true>),
        hipFuncAttributeMaxDynamicSharedMemorySize, SMEM_MAIN);
    if (rc == hipSuccess) {
        dnc_kernel<true><<<dim3(Bb), dim3(1024), SMEM_MAIN, stream>>>(
            x, b1, b2, bif, wp, memg, linkg, out);
    } else {
        dnc_kernel<false><<<dim3(Bb), dim3(1024), SMEM_FB, stream>>>(
            x, b1, b2, bif, wp, memg, linkg, out);
    }
}

// Round 9
// 2329.469 us; speedup vs baseline: 4.0181x; 1.2103x over previous
//
#include <hip/hip_runtime.h>
#include <hip/hip_fp16.h>
#include <math.h>

#define Tt 64
#define Bb 16
#define Nn 256
#define Ww 64
#define Rr 4
#define INd 64
#define OUTd 64
#define IFS 471
#define EPSf 1e-6f

// packed half2 weight layout offsets (in half2 units), pairs along K
#define W1OFF   0        // 160*256
#define W2OFF   40960    // 128*256
#define WIFOFF  73728    // 128*471
#define WOUTOFF 134016   // 128*64
#define WMEMOFF 142208   // 128*64
#define WTOT    150400

// link: 256 rows x 129 dwords (258 halfs; 256 used + 2 pad)
#define LROW    129
#define LINKB   (256 * LROW * 4)     // 132096 B
#define SCRB    16384                // 4096 floats / 8192 halfs
#define FIXF    3760
#define SMEM_MAIN (LINKB + SCRB + FIXF * 4)   // 163520 <= 163840
#define SMEM_FB   (SCRB + FIXF * 4)

typedef _Float16 h2v __attribute__((ext_vector_type(2)));
__device__ __forceinline__ float fdot2(__half2 a, __half2 b, float c) {
    return __builtin_amdgcn_fdot2(*(h2v*)&a, *(h2v*)&b, c, false);
}
__device__ __forceinline__ __half2 pkh(float a, float b) {
    auto r = __builtin_amdgcn_cvt_pkrtz(a, b);   // __fp16 ext_vector(2)
    return *(__half2*)&r;
}

__device__ __forceinline__ float sigm(float x) { return 1.f / (1.f + expf(-x)); }
__device__ __forceinline__ float oneplus_(float x) {
    return 1.f + fmaxf(x, 0.f) + log1pf(expf(-fabsf(x)));
}
__device__ __forceinline__ float wsum(float v) {
#pragma unroll
    for (int o = 32; o; o >>= 1) v += __shfl_xor(v, o, 64);
    return v;
}
__device__ __forceinline__ float wmaxr(float v) {
#pragma unroll
    for (int o = 32; o; o >>= 1) v = fmaxf(v, __shfl_xor(v, o, 64));
    return v;
}

// shared GEMV-partial body: half2 weight column (runtime stride) dot half2
// vector in LDS via v_dot2_f32_f16. noinline -> one icache copy.
__device__ __attribute__((noinline)) float gemv_part(
    const __half2* __restrict__ wP, int stride, int iters,
    const __half2* __restrict__ vin)
{
    float a[8] = {0.f,0.f,0.f,0.f,0.f,0.f,0.f,0.f};
#pragma unroll 1
    for (int j0 = 0; j0 < iters; j0 += 8) {
        __half2 hh[8], vv[8];
#pragma unroll
        for (int u = 0; u < 8; ++u) hh[u] = wP[(j0 + u) * stride];
#pragma unroll
        for (int u = 0; u < 8; ++u) vv[u] = vin[j0 + u];
#pragma unroll
        for (int u = 0; u < 8; ++u) a[u] = fdot2(hh[u], vv[u], a[u]);
    }
    return ((a[0]+a[1])+(a[2]+a[3])) + ((a[4]+a[5])+(a[6]+a[7]));
}

// ---- converter: fp32 weights -> packed half2 (pairs along K) ----
__global__ void convert_weights(const float* __restrict__ W1, const float* __restrict__ W2,
                                const float* __restrict__ Wif, const float* __restrict__ Wout,
                                const float* __restrict__ Wmem, __half2* __restrict__ wp) {
    int i = blockIdx.x * blockDim.x + threadIdx.x;
    if (i >= WTOT) return;
    float a, b;
    if (i < W2OFF)        { int r = i;           int k2 = r >> 8, n = r & 255; a = W1[(2*k2)*256+n];  b = W1[(2*k2+1)*256+n]; }
    else if (i < WIFOFF)  { int t = i - W2OFF;   int k2 = t >> 8, n = t & 255; a = W2[(2*k2)*256+n];  b = W2[(2*k2+1)*256+n]; }
    else if (i < WOUTOFF) { int t = i - WIFOFF;  int k2 = t / IFS, o = t - IFS*k2; a = Wif[(2*k2)*IFS+o]; b = Wif[(2*k2+1)*IFS+o]; }
    else if (i < WMEMOFF) { int t = i - WOUTOFF; int k2 = t >> 6, n = t & 63;  a = Wout[(2*k2)*64+n]; b = Wout[(2*k2+1)*64+n]; }
    else                  { int t = i - WMEMOFF; int k2 = t >> 6, n = t & 63;  a = Wmem[(2*k2)*64+n]; b = Wmem[(2*k2+1)*64+n]; }
    wp[i] = __floats2half2_rn(a, b);
}

template <bool LLINK>
__global__ __launch_bounds__(1024) void dnc_kernel(
    const float* __restrict__ x, const float* __restrict__ b1,
    const float* __restrict__ b2, const float* __restrict__ bif,
    const __half2* __restrict__ wp,
    __half* __restrict__ memg,      // per batch 64*256 halves, [w][n]
    __half2* __restrict__ linkg,    // fallback link
    float* __restrict__ out)
{
    extern __shared__ __align__(16) char smem[];
    const int b = blockIdx.x;
    const int tid = threadIdx.x;
    const int lane = tid & 63;
    const int wv = tid >> 6;

    __half2* l2p = (__half2*)smem;
    __half2* gl2 = linkg + (size_t)b * (256 * LROW);
    float* scr   = (float*)(smem + (LLINK ? LINKB : 0));
    __half* scrh = (__half*)scr;
    float* fx    = (float*)((char*)scr + SCRB);

    float*   s_rw    = fx + 0;                    // 1024 [n][r] fp32
    __half2* s_ctrlh = (__half2*)(fx + 1024);     // 160: [0,32) x pairs, [32,160) rvec pairs
    __half2* s_hh    = (__half2*)(fx + 1184);     // 128
    __half2* s_nnh   = (__half2*)(fx + 1312);     // 128
    __half2* s_rwh   = (__half2*)(fx + 1440);     // 512 [r][128 n-pairs]
    float* s_z     = fx + 1952;   // 472
    float* s_usage = fx + 2424;   // 256
    float* s_ww    = fx + 2680;   // 256
    float* s_prec  = fx + 2936;   // 256
    float* s_wcdot = fx + 3192;   // 256
    float* s_wcss  = fx + 3448;   // 256
    float* s_knorm = fx + 3704;   // 4
    float* s_rstr  = fx + 3708;   // 4
    float* s_rmode = fx + 3712;   // 12
    float* s_sc    = fx + 3724;   // 4
    float* s_red   = fx + 3728;   // 32
    float* s_srt   = scr + 1024;  // 256 (mega only)
    float* s_cp    = scr + 1280;  // 256 (mega only)

    const float4* rw4 = (const float4*)s_rw;
    __half*  memh  = memg + (size_t)b * (Ww * Nn);
    __half2* memh2 = (__half2*)memh;

    auto lread = [&](int idx) -> __half2 {
        if constexpr (LLINK) return l2p[idx]; else return gl2[idx];
    };
    auto lwrite = [&](int idx, __half2 v) {
        if constexpr (LLINK) l2p[idx] = v; else gl2[idx] = v;
    };

    // ---- init (ws/LDS poisoned before every launch) ----
    {
        __half2 z2 = pkh(0.f, 0.f);
#pragma unroll 1
        for (int i = tid; i < 256 * LROW; i += 1024) lwrite(i, z2);
        __half2 e2 = __floats2half2_rn(EPSf, EPSf);
#pragma unroll 1
        for (int j = 0; j < 8; ++j) memh2[tid + j * 1024] = e2;
        if (tid < 512) s_rwh[tid] = z2;
        if (tid < 32) {
            float2 xv = *(const float2*)&x[b * INd + 2 * tid];
            s_ctrlh[tid] = pkh(xv.x, xv.y);
        } else if (tid < 160) s_ctrlh[tid] = z2;
    }
    if (tid < 256) {
        s_usage[tid] = 0.f; s_ww[tid] = 0.f; s_prec[tid] = 0.f;
        s_rw[tid*4+0] = 0.f; s_rw[tid*4+1] = 0.f; s_rw[tid*4+2] = 0.f; s_rw[tid*4+3] = 0.f;
    }

#pragma unroll 1
    for (int t = 0; t < Tt; ++t) {
        __syncthreads();  // B0

        // ---- P1: GEMV1 partials (wave-uniform K-split 4) ----
        {
            int kc = wv >> 2, o = (wv & 3) * 64 + lane;
            scr[kc * 256 + o] = gemv_part(wp + W1OFF + kc * 40 * 256 + o, 256, 40,
                                          s_ctrlh + kc * 40);
        }
        __syncthreads();  // B1
        if (tid < 256) {
            float v = tanhf(b1[tid] + ((scr[tid] + scr[256+tid]) + (scr[512+tid] + scr[768+tid])));
            float pv = __shfl_xor(v, 1, 64);
            if ((tid & 1) == 0) s_hh[tid >> 1] = pkh(v, pv);
        }
        __syncthreads();  // B2

        // ---- P2: GEMV2 partials ----
        {
            int kc = wv >> 2, o = (wv & 3) * 64 + lane;
            scr[kc * 256 + o] = gemv_part(wp + W2OFF + kc * 32 * 256 + o, 256, 32,
                                          s_hh + kc * 32);
        }
        __syncthreads();  // B3
        if (tid < 256) {
            float v = tanhf(b2[tid] + ((scr[tid] + scr[256+tid]) + (scr[512+tid] + scr[768+tid])));
            float pv = __shfl_xor(v, 1, 64);
            if ((tid & 1) == 0) s_nnh[tid >> 1] = pkh(v, pv);
        }
        __syncthreads();  // B4

        // ---- P3: GEMV3 partials (K-split 2) ----
        {
            int kc = wv >> 3, o = (wv & 7) * 64 + lane;
            if (o < IFS)
                scr[kc * 512 + o] = gemv_part(wp + WIFOFF + kc * 64 * IFS + o, IFS, 64,
                                              s_nnh + kc * 64);
        }
        __syncthreads();  // B5
        if (tid < IFS) s_z[tid] = bif[tid] + scr[tid] + scr[512 + tid];
        __syncthreads();  // B6

        // ---- P4: scalars + usage + wc dot/ss (merged wave roles) ----
        if (wv < 4) {
            float vz = s_z[lane * 4 + wv];
            float s = wsum(vz * vz);
            if (lane == 0) s_knorm[wv] = sqrtf(s) + EPSf;
        } else if (wv == 4) {
            float vz = s_z[260 + lane];
            float s = wsum(vz * vz);
            if (lane == 0) s_sc[3] = sqrtf(s) + EPSf;
        } else if (wv == 5) {
            if (lane < 4) s_rstr[lane] = oneplus_(s_z[256 + lane]);
            else if (lane >= 8 && lane < 12) {
                int r = lane - 8;
                float a = s_z[459+r], bm = s_z[463+r], c = s_z[467+r];
                float mx = fmaxf(a, fmaxf(bm, c));
                float ea = expf(a-mx), eb = expf(bm-mx), ec = expf(c-mx);
                float inv = 1.f / ((ea+eb)+ec);
                s_rmode[0*4+r] = ea*inv; s_rmode[1*4+r] = eb*inv; s_rmode[2*4+r] = ec*inv;
            } else if (lane == 16) s_sc[0] = oneplus_(s_z[324]);
            else if (lane == 17) s_sc[1] = sigm(s_z[457]);
            else if (lane == 18) s_sc[2] = sigm(s_z[458]);
        } else if (wv >= 8 && wv < 12) {
            int n = tid - 512;
            float ret = 1.f;
#pragma unroll
            for (int r = 0; r < 4; ++r) {
                float fg = sigm(s_z[453 + r]);
                ret *= 1.f - fg * s_rw[n*4 + r];
            }
            float u = s_usage[n], wwo = s_ww[n];
            s_usage[n] = (u + wwo - u * wwo) * ret;
        } else if (wv >= 12) {
            int n = tid - 768;
            float dot = 0.f, ssv = 0.f;
#pragma unroll 1
            for (int w0 = 0; w0 < 64; w0 += 8) {
                __half hv[8];
#pragma unroll
                for (int u = 0; u < 8; ++u) hv[u] = memh[(w0 + u) * 256 + n];
#pragma unroll
                for (int u = 0; u < 8; ++u) {
                    float m = __half2float(hv[u]);
                    ssv = fmaf(m, m, ssv);
                    dot = fmaf(m, s_z[260 + w0 + u], dot);
                }
            }
            s_wcdot[n] = dot; s_wcss[n] = ssv;
        }
        __syncthreads();  // B7

        // ---- P5: rank partials ----
        {
            int q = tid >> 8, n = tid & 255;
            float un = s_usage[n];
            float cnt = 0.f;
            int j0 = q * 64;
#pragma unroll 1
            for (int j = j0; j < j0 + 64; ++j) {
                float uj = s_usage[j];
                if (uj < un || (uj == un && j < n)) cnt += 1.f;
            }
            scr[q * 256 + n] = cnt;
        }
        __syncthreads();  // B8

        // ---- P6: mega (wave 0) ----
        if (wv == 0) {
            int rk[4]; float uu[4];
#pragma unroll
            for (int i = 0; i < 4; ++i) {
                int n = lane * 4 + i;
                float c = scr[n] + scr[256+n] + scr[512+n] + scr[768+n];
                rk[i] = (int)(c + 0.5f);
                uu[i] = s_usage[n];
                s_srt[rk[i]] = uu[i];
            }
            float4 vs = ((const float4*)s_srt)[lane];
            float p1 = vs.x * vs.y, p2 = p1 * vs.z, tot = p2 * vs.w;
            float incl = tot;
#pragma unroll
            for (int off = 1; off < 64; off <<= 1) {
                float tv = __shfl_up(incl, off, 64);
                if (lane >= off) incl *= tv;
            }
            float excl = __shfl_up(incl, 1, 64);
            if (lane == 0) excl = 1.f;
            float4 o4v; o4v.x = excl; o4v.y = excl*vs.x; o4v.z = excl*p1; o4v.w = excl*p2;
            ((float4*)s_cp)[lane] = o4v;

            float sims[4], mx = -1e30f;
#pragma unroll
            for (int i = 0; i < 4; ++i) {
                int n = lane * 4 + i;
                sims[i] = s_wcdot[n] / ((sqrtf(s_wcss[n]) + EPSf) * s_sc[3]) * s_sc[0];
                mx = fmaxf(mx, sims[i]);
            }
            mx = wmaxr(mx);
            float es[4], ls = 0.f;
#pragma unroll
            for (int i = 0; i < 4; ++i) { es[i] = expf(sims[i] - mx); ls += es[i]; }
            ls = wsum(ls);
            float ag = s_sc[1], wg = s_sc[2], inv = 1.f / ls, lw = 0.f;
#pragma unroll
            for (int i = 0; i < 4; ++i) {
                int n = lane * 4 + i;
                float alloc = (1.f - uu[i]) * s_cp[rk[i]];
                float wwn = wg * (ag * alloc + (1.f - ag) * es[i] * inv);
                s_ww[n] = wwn; lw += wwn;
            }
            lw = wsum(lw);
            if (lane == 0) s_red[0] = lw;
        }
        __syncthreads();  // B9

        // ---- P7: link col pass (8 waves; bwd via fdot2) || mem RMW (8 waves) ----
        if (tid < 512) {
            int kc = tid >> 7, p = tid & 127;
            int c0 = 2 * p, c1 = c0 + 1;
            float wwc0 = s_ww[c0], wwc1 = s_ww[c1];
            float pt0 = s_prec[c0], pt1 = s_prec[c1];
            float acc[8] = {0,0,0,0,0,0,0,0};
            int kbase = kc * 64;
#pragma unroll 1
            for (int k0 = kbase; k0 < kbase + 64; k0 += 8) {
                __half2 lv[8];
#pragma unroll
                for (int u = 0; u < 8; ++u) lv[u] = lread((k0 + u) * LROW + p);
                float l0v[8], l1v[8];
#pragma unroll
                for (int u = 0; u < 8; ++u) {
                    int k = k0 + u;
                    float wk = s_ww[k];
                    float2 lf = __half22float2(lv[u]);
                    float l0 = (1.f - wk - wwc0) * lf.x + wk * pt0;
                    float l1 = (1.f - wk - wwc1) * lf.y + wk * pt1;
                    if (k == c0) l0 = 0.f;
                    if (k == c1) l1 = 0.f;
                    l0v[u] = l0; l1v[u] = l1;
                }
#pragma unroll
                for (int u = 0; u < 8; ++u)
                    lwrite((k0 + u) * LROW + p, pkh(l0v[u], l1v[u]));
                __half2 l0p[4], l1p[4];
#pragma unroll
                for (int i = 0; i < 4; ++i) {
                    l0p[i] = pkh(l0v[2*i], l0v[2*i+1]);
                    l1p[i] = pkh(l1v[2*i], l1v[2*i+1]);
                }
                int kp0 = k0 >> 1;
#pragma unroll
                for (int r = 0; r < 4; ++r) {
                    __half2 rp[4];
#pragma unroll
                    for (int i = 0; i < 4; ++i) rp[i] = s_rwh[r * 128 + kp0 + i];
#pragma unroll
                    for (int i = 0; i < 4; ++i) {
                        acc[r]     = fdot2(l0p[i], rp[i], acc[r]);
                        acc[4 + r] = fdot2(l1p[i], rp[i], acc[4 + r]);
                    }
                }
            }
            __half2* bp = (__half2*)scrh + (kc * 128 + p) * 4;
            bp[0] = pkh(acc[0], acc[1]);
            bp[1] = pkh(acc[2], acc[3]);
            bp[2] = pkh(acc[4], acc[5]);
            bp[3] = pkh(acc[6], acc[7]);
        } else {
            int t0 = tid - 512;
#pragma unroll 1
            for (int jb = 0; jb < 2; ++jb) {
                __half2 mv[8];
#pragma unroll
                for (int j = 0; j < 8; ++j) mv[j] = memh2[t0 + (jb * 8 + j) * 512];
#pragma unroll
                for (int j = 0; j < 8; ++j) {
                    int i2 = t0 + (jb * 8 + j) * 512;
                    int w = i2 >> 7, n2 = i2 & 127;
                    float er = sigm(s_z[325 + w]);
                    float wvv = s_z[389 + w];
                    float2 mf = __half22float2(mv[j]);
                    float wa = s_ww[2*n2], wb = s_ww[2*n2 + 1];
                    mf.x = mf.x * (1.f - wa * er) + wa * wvv;
                    mf.y = mf.y * (1.f - wb * er) + wb * wvv;
                    memh2[i2] = __floats2half2_rn(mf.x, mf.y);
                }
            }
        }
        __syncthreads();  // B10

        // ---- P8: fwd row pass (fdot2, no unpack) + prec update ----
        {
            int q = tid >> 8, n8 = tid & 255;
            float f[4] = {0.f, 0.f, 0.f, 0.f};
            int base = n8 * LROW + q * 32;
#pragma unroll 1
            for (int j0 = 0; j0 < 32; j0 += 8) {
                __half2 lv[8];
#pragma unroll
                for (int u = 0; u < 8; ++u) lv[u] = lread(base + j0 + u);
#pragma unroll
                for (int r = 0; r < 4; ++r) {
                    __half2 rp[8];
#pragma unroll
                    for (int u = 0; u < 8; ++u) rp[u] = s_rwh[r * 128 + q * 32 + j0 + u];
#pragma unroll
                    for (int u = 0; u < 8; ++u) f[r] = fdot2(lv[u], rp[u], f[r]);
                }
            }
            __half2* fp2 = (__half2*)(scrh + 4096) + (q * 256 + n8) * 2;
            fp2[0] = pkh(f[0], f[1]);
            fp2[1] = pkh(f[2], f[3]);
            if (q == 0) s_prec[n8] = (1.f - s_red[0]) * s_prec[n8] + s_ww[n8];
        }
        __syncthreads();  // B11

        // ---- P9: rc sim + bwd/fwd reduce ----
        int rr = tid >> 8, n8c = tid & 255;
        float bwv = 0.f, fwv = 0.f, e_rc = 0.f, sim;
        {
#pragma unroll
            for (int kc = 0; kc < 4; ++kc)
                bwv += __half2float(scrh[(kc * 128 + (n8c >> 1)) * 8 + (n8c & 1) * 4 + rr]);
#pragma unroll
            for (int qq = 0; qq < 4; ++qq)
                fwv += __half2float(scrh[4096 + (qq * 256 + n8c) * 4 + rr]);
            float ssv = 0.f, dv = 0.f;
#pragma unroll 1
            for (int w0 = 0; w0 < 64; w0 += 8) {
                __half hv[8];
#pragma unroll
                for (int u = 0; u < 8; ++u) hv[u] = memh[(w0 + u) * 256 + n8c];
#pragma unroll
                for (int u = 0; u < 8; ++u) {
                    float m = __half2float(hv[u]);
                    ssv = fmaf(m, m, ssv);
                    dv = fmaf(m, s_z[(w0 + u) * 4 + rr], dv);
                }
            }
            sim = dv / ((sqrtf(ssv) + EPSf) * s_knorm[rr]) * s_rstr[rr];
            float mx = wmaxr(sim);
            if (lane == 0) s_red[wv] = mx;
        }
        __syncthreads();  // B12
        {
            float mx = fmaxf(fmaxf(s_red[rr*4+0], s_red[rr*4+1]), fmaxf(s_red[rr*4+2], s_red[rr*4+3]));
            e_rc = expf(sim - mx);
            float s = wsum(e_rc);
            if (lane == 0) s_red[16 + wv] = s;
        }
        __syncthreads();  // B13
        {
            float sm = (s_red[16+rr*4+0] + s_red[16+rr*4+1]) + (s_red[16+rr*4+2] + s_red[16+rr*4+3]);
            float rc = e_rc / sm;
            float v = bwv * s_rmode[0*4+rr] + rc * s_rmode[1*4+rr] + fwv * s_rmode[2*4+rr];
            s_rw[n8c*4 + rr] = v;
            float pv = __shfl_xor(v, 1, 64);
            if ((n8c & 1) == 0) s_rwh[rr * 128 + (n8c >> 1)] = pkh(v, pv);
        }
        __syncthreads();  // B14

        // ---- P12: rvec partials ----
        {
            int kc = tid >> 8, o = tid & 255, w = o >> 2, r = o & 3;
            const __half* mw = memh + w * 256 + kc * 64;
            float a = 0.f;
#pragma unroll 1
            for (int j0 = 0; j0 < 64; j0 += 8) {
                __half hv[8];
#pragma unroll
                for (int u = 0; u < 8; ++u) hv[u] = mw[j0 + u];
#pragma unroll
                for (int u = 0; u < 8; ++u)
                    a = fmaf(__half2float(hv[u]), s_rw[(kc * 64 + j0 + u) * 4 + r], a);
            }
            scr[kc * 256 + o] = a;
        }
        __syncthreads();  // B15

        // ---- P13: rvec reduce -> ctrl pairs + next-x staging ----
        if (tid < 256) {
            float v = (scr[tid] + scr[256+tid]) + (scr[512+tid] + scr[768+tid]);
            float pv = __shfl_xor(v, 1, 64);
            if ((tid & 1) == 0) s_ctrlh[32 + (tid >> 1)] = pkh(v, pv);
        } else if (tid >= 512 && tid < 544) {
            if (t + 1 < Tt) {
                int i = tid - 512;
                float2 xv = *(const float2*)&x[((t + 1) * Bb + b) * INd + 2 * i];
                s_ctrlh[i] = pkh(xv.x, xv.y);
            }
        }
        __syncthreads();  // B16

        // ---- P14: out GEMV partials (shared gemv_part; rvec read from ctrl pairs) ----
        {
            int c4 = wv, o4 = lane;
            const __half2* wsrc = (c4 < 8) ? (wp + WOUTOFF + (c4 * 16) * 64 + o4)
                                           : (wp + WMEMOFF + ((c4 - 8) * 16) * 64 + o4);
            const __half2* vsrc = (c4 < 8) ? (s_nnh + c4 * 16)
                                           : (s_ctrlh + 32 + (c4 - 8) * 16);
            scr[c4 * 64 + o4] = gemv_part(wsrc, 64, 16, vsrc);
        }
        __syncthreads();  // B17
        if (tid < 64) {
            float s = 0.f;
#pragma unroll
            for (int g = 0; g < 16; ++g) s += scr[g * 64 + tid];
            out[(t * Bb + b) * OUTd + tid] = s;
        }
        // loop-top barrier covers remaining hazards
    }
}

extern "C" void kernel_launch(void* const* d_in, const int* in_sizes, int n_in,
                              void* d_out, int out_size, void* d_ws, size_t ws_size,
                              hipStream_t stream) {
    const float* x    = (const float*)d_in[0];
    const float* W1   = (const float*)d_in[1];
    const float* b1   = (const float*)d_in[2];
    const float* W2   = (const float*)d_in[3];
    const float* b2   = (const float*)d_in[4];
    const float* Wif  = (const float*)d_in[5];
    const float* bif  = (const float*)d_in[6];
    const float* Wout = (const float*)d_in[7];
    const float* Wmem = (const float*)d_in[8];
    float* out = (float*)d_out;

    // ws: [0, 601600) packed half2 weights; [601600, +512KB) mem fp16; then fallback link.
    char* ws = (char*)d_ws;
    __half2* wp    = (__half2*)ws;
    __half*  memg  = (__half*)(ws + 601600);
    __half2* linkg = (__half2*)(ws + 601600 + 524288);

    convert_weights<<<dim3((WTOT + 255) / 256), dim3(256), 0, stream>>>(W1, W2, Wif, Wout, Wmem, wp);

    hipError_t rc = hipFuncSetAttribute(
        reinterpret_cast<const void*>(&dnc_kernel<true>),
        hipFuncAttributeMaxDynamicSharedMemorySize, SMEM_MAIN);
    if (rc == hipSuccess) {
        dnc_kernel<true><<<dim3(Bb), dim3(1024), SMEM_MAIN, stream>>>(
            x, b1, b2, bif, wp, memg, linkg, out);
    } else {
        dnc_kernel<false><<<dim3(Bb), dim3(1024), SMEM_FB, stream>>>(
            x, b1, b2, bif, wp, memg, linkg, out);
    }
}